// Round 1
// baseline (936.289 us; speedup 1.0000x reference)
//
#include <hip/hip_runtime.h>
#include <hip/hip_bf16.h>
#include <stdint.h>

// ---------------------------------------------------------------------------
// TransformerBlock: rms1 -> QKV(+RoPE) -> window-512 flash attn -> out-proj(+x)
//                   -> rms2(+gate logits) -> top2 route -> grouped SwiGLU MoE -> +x2
// Round 1: correctness-first. bf16 MFMA 16x16x32 everywhere, reg-staged LDS,
// XOR-swizzled tiles. Weights transposed+converted to bf16 [N][K] per launch.
// ---------------------------------------------------------------------------

#define S_ 2048
#define HID_ 1024
#define NH_ 16
#define HD_ 64
#define WIN_ 512
#define DFF_ 4096
#define NE_ 8

typedef unsigned short u16;
typedef __attribute__((ext_vector_type(8))) short short8;
typedef __attribute__((ext_vector_type(4))) float f32x4;

__device__ __forceinline__ u16 f2bf(float f) {
  union { float f; unsigned u; } v; v.f = f;
  unsigned r = (v.u + 0x7FFFu + ((v.u >> 16) & 1u)) >> 16;
  return (u16)r;
}
__device__ __forceinline__ float bf2f(u16 b) {
  union { unsigned u; float f; } v; v.u = ((unsigned)b) << 16;
  return v.f;
}

// ------------------------- weight transpose+convert -------------------------
// W f32 [K][N]  ->  WT bf16 [N][K].  grid(N/64, K/64, nmat), 256 thr.
__global__ __launch_bounds__(256) void convT_f32_k(const float* __restrict__ W,
                                                   u16* __restrict__ WT,
                                                   int K, int N, size_t matStride) {
  __shared__ u16 t[64][66];
  const float* Wm = W + (size_t)blockIdx.z * matStride;
  u16* WTm = WT + (size_t)blockIdx.z * matStride;
  int n0 = blockIdx.x * 64, k0 = blockIdx.y * 64;
  int tid = threadIdx.x;
  int c2 = (tid & 31) * 2, rr = tid >> 5;
#pragma unroll
  for (int it = 0; it < 8; ++it) {
    int r = it * 8 + rr;
    float2 ab = *(const float2*)&Wm[(size_t)(k0 + r) * N + n0 + c2];
    t[c2][r] = f2bf(ab.x);
    t[c2 + 1][r] = f2bf(ab.y);
  }
  __syncthreads();
#pragma unroll
  for (int it = 0; it < 8; ++it) {
    int n = it * 8 + rr;
    unsigned pk = (unsigned)t[n][c2] | ((unsigned)t[n][c2 + 1] << 16);
    *(unsigned*)&WTm[(size_t)(n0 + n) * K + k0 + c2] = pk;
  }
}

// bf16 [K][N] -> bf16 [N][K] (for V: [s][d] -> [d][s] per head)
__global__ __launch_bounds__(256) void convT_u16_k(const u16* __restrict__ W,
                                                   u16* __restrict__ WT,
                                                   int K, int N, size_t matStride) {
  __shared__ u16 t[64][66];
  const u16* Wm = W + (size_t)blockIdx.z * matStride;
  u16* WTm = WT + (size_t)blockIdx.z * matStride;
  int n0 = blockIdx.x * 64, k0 = blockIdx.y * 64;
  int tid = threadIdx.x;
  int c2 = (tid & 31) * 2, rr = tid >> 5;
#pragma unroll
  for (int it = 0; it < 8; ++it) {
    int r = it * 8 + rr;
    unsigned vv = *(const unsigned*)&Wm[(size_t)(k0 + r) * N + n0 + c2];
    t[c2][r] = (u16)vv;
    t[c2 + 1][r] = (u16)(vv >> 16);
  }
  __syncthreads();
#pragma unroll
  for (int it = 0; it < 8; ++it) {
    int n = it * 8 + rr;
    unsigned pk = (unsigned)t[n][c2] | ((unsigned)t[n][c2 + 1] << 16);
    *(unsigned*)&WTm[(size_t)(n0 + n) * K + k0 + c2] = pk;
  }
}

// ------------------------------- rope tables --------------------------------
// cos[s][j] = R[s][2j][2j], sin[s][j] = R[s][2j+1][2j]
__global__ __launch_bounds__(256) void rope_tab_k(const float* __restrict__ rot,
                                                  float* __restrict__ cost,
                                                  float* __restrict__ sint) {
  int id = blockIdx.x * 256 + threadIdx.x;
  if (id >= S_ * 32) return;
  int s = id >> 5, j = id & 31;
  cost[id] = rot[(size_t)s * 4096 + (size_t)(2 * j) * 64 + 2 * j];
  sint[id] = rot[(size_t)s * 4096 + (size_t)(2 * j + 1) * 64 + 2 * j];
}

// --------------------------------- rmsnorm 1 --------------------------------
__global__ __launch_bounds__(256) void rms1_k(const float* __restrict__ x,
                                              const float* __restrict__ rw,
                                              u16* __restrict__ y) {
  int row = blockIdx.x, tid = threadIdx.x;
  const float4 v = *(const float4*)&x[(size_t)row * HID_ + tid * 4];
  float ss = v.x * v.x + v.y * v.y + v.z * v.z + v.w * v.w;
#pragma unroll
  for (int o = 32; o; o >>= 1) ss += __shfl_xor(ss, o);
  __shared__ float red[4];
  if ((tid & 63) == 0) red[tid >> 6] = ss;
  __syncthreads();
  float rstd = rsqrtf((red[0] + red[1] + red[2] + red[3]) * (1.f / HID_) + 1e-6f);
  const float4 w4 = *(const float4*)&rw[tid * 4];
  ushort4 o4;
  o4.x = f2bf(v.x * rstd * w4.x);
  o4.y = f2bf(v.y * rstd * w4.y);
  o4.z = f2bf(v.z * rstd * w4.z);
  o4.w = f2bf(v.w * rstd * w4.w);
  *(ushort4*)&y[(size_t)row * HID_ + tid * 4] = o4;
}

// ------------------------- rmsnorm 2 + gate logits --------------------------
__global__ __launch_bounds__(256) void rms2_gate_k(const float* __restrict__ x2,
                                                   const float* __restrict__ rw,
                                                   const float* __restrict__ gw,
                                                   u16* __restrict__ y2,
                                                   float* __restrict__ logits) {
  int row = blockIdx.x, tid = threadIdx.x;
  int wv = tid >> 6, ln = tid & 63;
  const float4 v = *(const float4*)&x2[(size_t)row * HID_ + tid * 4];
  float ss = v.x * v.x + v.y * v.y + v.z * v.z + v.w * v.w;
#pragma unroll
  for (int o = 32; o; o >>= 1) ss += __shfl_xor(ss, o);
  __shared__ float red[4];
  __shared__ float lred[4][8];
  if (ln == 0) red[wv] = ss;
  __syncthreads();
  float rstd = rsqrtf((red[0] + red[1] + red[2] + red[3]) * (1.f / HID_) + 1e-6f);
  const float4 w4 = *(const float4*)&rw[tid * 4];
  float yv[4];
  yv[0] = v.x * rstd * w4.x; yv[1] = v.y * rstd * w4.y;
  yv[2] = v.z * rstd * w4.z; yv[3] = v.w * rstd * w4.w;
  ushort4 o4;
  o4.x = f2bf(yv[0]); o4.y = f2bf(yv[1]); o4.z = f2bf(yv[2]); o4.w = f2bf(yv[3]);
  *(ushort4*)&y2[(size_t)row * HID_ + tid * 4] = o4;
  // gate logits
  float le[8] = {0, 0, 0, 0, 0, 0, 0, 0};
  int d0 = tid * 4;
#pragma unroll
  for (int j = 0; j < 4; ++j) {
    const float* grow = &gw[(size_t)(d0 + j) * NE_];
#pragma unroll
    for (int e = 0; e < 8; ++e) le[e] += yv[j] * grow[e];
  }
#pragma unroll
  for (int e = 0; e < 8; ++e) {
    float t = le[e];
#pragma unroll
    for (int o = 32; o; o >>= 1) t += __shfl_xor(t, o);
    le[e] = t;
  }
  if (ln == 0)
#pragma unroll
    for (int e = 0; e < 8; ++e) lred[wv][e] = le[e];
  __syncthreads();
  if (tid < 8)
    logits[(size_t)row * NE_ + tid] =
        lred[0][tid] + lred[1][tid] + lred[2][tid] + lred[3][tid];
}

// ------------------------------ top-2 routing -------------------------------
__global__ __launch_bounds__(256) void topk_k(const float* __restrict__ logits,
                                              int* __restrict__ topi,
                                              float* __restrict__ topg,
                                              int* __restrict__ counts) {
  int t = blockIdx.x * 256 + threadIdx.x;
  if (t >= S_) return;
  const float* lg = &logits[(size_t)t * NE_];
  float v0 = -1e30f; int i0 = 0;
#pragma unroll
  for (int e = 0; e < 8; ++e) {
    float x = lg[e];
    if (x > v0) { v0 = x; i0 = e; }
  }
  float v1 = -1e30f; int i1 = 0;
#pragma unroll
  for (int e = 0; e < 8; ++e) {
    if (e == i0) continue;
    float x = lg[e];
    if (x > v1) { v1 = x; i1 = e; }
  }
  float e1 = __expf(v1 - v0);
  topi[t * 2] = i0; topi[t * 2 + 1] = i1;
  topg[t * 2] = 1.f / (1.f + e1);
  topg[t * 2 + 1] = e1 / (1.f + e1);
  atomicAdd(&counts[i0], 1);
  atomicAdd(&counts[i1], 1);
}

__global__ void prefix_k(const int* __restrict__ counts, int* __restrict__ ebase) {
  if (threadIdx.x == 0) {
    int s = 0;
    for (int e = 0; e < 8; ++e) { ebase[e] = s; s += counts[e]; }
  }
}

__global__ __launch_bounds__(256) void scatter_k(const int* __restrict__ topi,
                                                 const int* __restrict__ ebase,
                                                 int* __restrict__ rank,
                                                 int* __restrict__ slot_token,
                                                 int* __restrict__ slot_of) {
  int t = blockIdx.x * 256 + threadIdx.x;
  if (t >= S_) return;
  for (int k = 0; k < 2; ++k) {
    int e = topi[t * 2 + k];
    int pos = ebase[e] + atomicAdd(&rank[e], 1);
    slot_token[pos] = t;
    slot_of[t * 2 + k] = pos;
  }
}

// --------------------------------- GEMM -------------------------------------
// 128x128 tile, BK=32, 4 waves (each 64x64 = 4x4 frags), double-buffered LDS,
// reg-staged, XOR-swizzled (unit ^= (row>>1)&3, rows are 64B = 4x16B units).
// MODE 0: qkv (z picks wq/wk/wv; rope for z<2; out head-major bf16)
// MODE 1: out-proj (+x residual, f32 out)
// MODE 2: ffn1 dual-B swiglu (gathered rows, out h bf16 [slot][4096])
// MODE 3: ffn2 (compact rows, out eo bf16 [slot][1024])
template <int MODE>
__global__ __launch_bounds__(256) void gemm_k(
    const u16* __restrict__ A, const u16* __restrict__ Bq,
    const u16* __restrict__ Bk, const u16* __restrict__ Bv, int K,
    const int* __restrict__ ecnt, const int* __restrict__ ebase,
    const int* __restrict__ slot_token, const float* __restrict__ cost,
    const float* __restrict__ sint, const float* __restrict__ xres,
    float* __restrict__ outf, u16* __restrict__ oq, u16* __restrict__ ok,
    u16* __restrict__ ov) {
  constexpr bool DUAL = (MODE == 2);
  __shared__ alignas(16) char smem[DUAL ? 49152 : 32768];
  char* As = smem;
  char* Bs = smem + 16384;
  char* Cs = smem + 32768;  // only used when DUAL

  int m0 = blockIdx.x * 128, n0 = blockIdx.y * 128;
  int cnt = 0, base = 0;
  const u16* Bbase;
  const u16* B2base = nullptr;
  u16* outb = oq;
  int rope = 0;
  if constexpr (MODE == 0) {
    int z = blockIdx.z;
    Bbase = (z == 0) ? Bq : (z == 1) ? Bk : Bv;
    outb = (z == 0) ? oq : (z == 1) ? ok : ov;
    rope = (z < 2) ? 1 : 0;
  } else if constexpr (MODE == 1) {
    Bbase = Bq;
  } else if constexpr (MODE == 2) {
    int e = blockIdx.z;
    cnt = ecnt[e]; base = ebase[e];
    if (m0 >= cnt) return;
    Bbase = Bq + (size_t)e * DFF_ * HID_;
    B2base = Bk + (size_t)e * DFF_ * HID_;
  } else {
    int e = blockIdx.z;
    cnt = ecnt[e]; base = ebase[e];
    if (m0 >= cnt) return;
    Bbase = Bq + (size_t)e * HID_ * DFF_;
  }

  int tid = threadIdx.x, w = tid >> 6, l = tid & 63, lo = l & 15, g = l >> 4;
  int wm = w & 1, wn = w >> 1;
  int KT = K >> 5;

  // staging geometry: lane covers rows rL and rL+16, unit l&3 (linear source)
  int rL = w * 32 + (l >> 2);
  int uSw = (l & 3) ^ ((rL >> 1) & 3);
  int wrOff0 = rL * 64 + uSw * 16;
  int wrOff1 = (rL + 16) * 64 + uSw * 16;

  const char *aSrc0, *aSrc1;
  if constexpr (MODE == 2) {
    int r0 = min(m0 + rL, cnt - 1), r1 = min(m0 + rL + 16, cnt - 1);
    aSrc0 = (const char*)(A + (size_t)slot_token[base + r0] * K) + (l & 3) * 16;
    aSrc1 = (const char*)(A + (size_t)slot_token[base + r1] * K) + (l & 3) * 16;
  } else if constexpr (MODE == 3) {
    int r0 = base + min(m0 + rL, cnt - 1), r1 = base + min(m0 + rL + 16, cnt - 1);
    aSrc0 = (const char*)(A + (size_t)r0 * K) + (l & 3) * 16;
    aSrc1 = (const char*)(A + (size_t)r1 * K) + (l & 3) * 16;
  } else {
    aSrc0 = (const char*)(A + (size_t)(m0 + rL) * K) + (l & 3) * 16;
    aSrc1 = (const char*)(A + (size_t)(m0 + rL + 16) * K) + (l & 3) * 16;
  }
  const char* bSrc0 = (const char*)(Bbase + (size_t)(n0 + rL) * K) + (l & 3) * 16;
  const char* bSrc1 = (const char*)(Bbase + (size_t)(n0 + rL + 16) * K) + (l & 3) * 16;
  const char *cSrc0 = nullptr, *cSrc1 = nullptr;
  if constexpr (DUAL) {
    cSrc0 = (const char*)(B2base + (size_t)(n0 + rL) * K) + (l & 3) * 16;
    cSrc1 = (const char*)(B2base + (size_t)(n0 + rL + 16) * K) + (l & 3) * 16;
  }

  f32x4 acc[4][4], acc2[DUAL ? 4 : 1][4];
#pragma unroll
  for (int i = 0; i < 4; ++i)
#pragma unroll
    for (int j = 0; j < 4; ++j) {
      acc[i][j] = (f32x4){0.f, 0.f, 0.f, 0.f};
      if constexpr (DUAL) acc2[i][j] = (f32x4){0.f, 0.f, 0.f, 0.f};
    }

  // prologue stage into buf 0
  {
    short8 a0 = *(const short8*)(aSrc0), a1 = *(const short8*)(aSrc1);
    short8 b0 = *(const short8*)(bSrc0), b1 = *(const short8*)(bSrc1);
    *(short8*)(As + wrOff0) = a0; *(short8*)(As + wrOff1) = a1;
    *(short8*)(Bs + wrOff0) = b0; *(short8*)(Bs + wrOff1) = b1;
    if constexpr (DUAL) {
      short8 c0 = *(const short8*)(cSrc0), c1 = *(const short8*)(cSrc1);
      *(short8*)(Cs + wrOff0) = c0; *(short8*)(Cs + wrOff1) = c1;
    }
  }
  __syncthreads();

  for (int kt = 0; kt < KT; ++kt) {
    int cur = kt & 1;
    bool pre = (kt + 1 < KT);
    short8 sa0, sa1, sb0, sb1, sc0, sc1;
    if (pre) {
      size_t kb = (size_t)(kt + 1) * 64;
      sa0 = *(const short8*)(aSrc0 + kb); sa1 = *(const short8*)(aSrc1 + kb);
      sb0 = *(const short8*)(bSrc0 + kb); sb1 = *(const short8*)(bSrc1 + kb);
      if constexpr (DUAL) {
        sc0 = *(const short8*)(cSrc0 + kb); sc1 = *(const short8*)(cSrc1 + kb);
      }
    }
    // compute on cur
    short8 af[4], bf_[4], cf[4];
#pragma unroll
    for (int mi = 0; mi < 4; ++mi) {
      int r = wm * 64 + mi * 16 + lo;
      af[mi] = *(const short8*)(As + cur * 8192 + r * 64 + ((g ^ ((r >> 1) & 3)) << 4));
    }
#pragma unroll
    for (int ni = 0; ni < 4; ++ni) {
      int r = wn * 64 + ni * 16 + lo;
      int off = cur * 8192 + r * 64 + ((g ^ ((r >> 1) & 3)) << 4);
      bf_[ni] = *(const short8*)(Bs + off);
      if constexpr (DUAL) cf[ni] = *(const short8*)(Cs + off);
    }
#pragma unroll
    for (int mi = 0; mi < 4; ++mi)
#pragma unroll
      for (int ni = 0; ni < 4; ++ni) {
        acc[mi][ni] = __builtin_amdgcn_mfma_f32_16x16x32_bf16(af[mi], bf_[ni], acc[mi][ni], 0, 0, 0);
        if constexpr (DUAL)
          acc2[mi][ni] = __builtin_amdgcn_mfma_f32_16x16x32_bf16(af[mi], cf[ni], acc2[mi][ni], 0, 0, 0);
      }
    if (pre) {
      char* Ad = As + (cur ^ 1) * 8192;
      char* Bd = Bs + (cur ^ 1) * 8192;
      *(short8*)(Ad + wrOff0) = sa0; *(short8*)(Ad + wrOff1) = sa1;
      *(short8*)(Bd + wrOff0) = sb0; *(short8*)(Bd + wrOff1) = sb1;
      if constexpr (DUAL) {
        char* Cd = Cs + (cur ^ 1) * 8192;
        *(short8*)(Cd + wrOff0) = sc0; *(short8*)(Cd + wrOff1) = sc1;
      }
    }
    __syncthreads();
  }

  // epilogue
#pragma unroll
  for (int mi = 0; mi < 4; ++mi) {
    int lr = wm * 64 + mi * 16 + g * 4;
#pragma unroll
    for (int ni = 0; ni < 4; ++ni) {
      int c = n0 + wn * 64 + ni * 16 + lo;
#pragma unroll
      for (int r = 0; r < 4; ++r) {
        float v = acc[mi][ni][r];
        if constexpr (MODE == 0) {
          int row = m0 + lr + r;
          float p = __shfl_xor(v, 1);
          if (rope) {
            int dd = c & 63;
            float co = cost[(size_t)row * 32 + (dd >> 1)];
            float si = sint[(size_t)row * 32 + (dd >> 1)];
            v = (dd & 1) ? (co * v - si * p) : (co * v + si * p);
          }
          outb[((size_t)(c >> 6) * S_ + row) * HD_ + (c & 63)] = f2bf(v);
        } else if constexpr (MODE == 1) {
          int row = m0 + lr + r;
          outf[(size_t)row * HID_ + c] = v + xres[(size_t)row * HID_ + c];
        } else if constexpr (MODE == 2) {
          int m = m0 + lr + r;
          if (m < cnt) {
            float v3 = acc2[mi][ni][r];
            float sg = v / (1.f + __expf(-v));
            outb[(size_t)(base + m) * DFF_ + c] = f2bf(sg * v3);
          }
        } else {
          int m = m0 + lr + r;
          if (m < cnt) outb[(size_t)(base + m) * HID_ + c] = f2bf(v);
        }
      }
    }
  }
}

// ------------------------------- attention ----------------------------------
// grid (32 q-tiles, 16 heads), 256 thr = 4 waves, each wave owns 16 q rows.
// S^T = K*Q^T (swapped) so each lane owns one q column; P via swizzled LDS.
__global__ __launch_bounds__(256) void attn_k(const u16* __restrict__ qh,
                                              const u16* __restrict__ kh,
                                              const u16* __restrict__ vht,
                                              u16* __restrict__ attn) {
  int qt = blockIdx.x, h = blockIdx.y;
  int tid = threadIdx.x, w = tid >> 6, l = tid & 63, lo = l & 15, g = l >> 4;
  __shared__ alignas(16) char Ks[8192];
  __shared__ alignas(16) char Vs[8192];
  __shared__ alignas(16) char Ps[8192];
  char* Pw = Ps + w * 2048;
  int q0 = qt * 64, qw = q0 + w * 16;
  const u16* qhh = qh + ((size_t)h * S_ + qw) * HD_;
  short8 bq0 = *(const short8*)(qhh + lo * 64 + g * 8);
  short8 bq1 = *(const short8*)(qhh + lo * 64 + 32 + g * 8);
  int q = qw + lo;
  float m_run = -1e30f, l_run = 0.f;
  f32x4 o[4];
#pragma unroll
  for (int i = 0; i < 4; ++i) o[i] = (f32x4){0.f, 0.f, 0.f, 0.f};
  int kt0 = max(0, q0 - (WIN_ - 1)) >> 6;
  for (int kt = kt0; kt <= qt; ++kt) {
    int kb = kt * 64;
    // stage K [key][d] and V^T [d][key], both swizzled (unit ^= row&7)
    {
      int r0 = w * 16 + (l >> 3), r1 = r0 + 8;
      int u = l & 7;
      short8 k0v = *(const short8*)(kh + ((size_t)h * S_ + kb + r0) * HD_ + u * 8);
      short8 k1v = *(const short8*)(kh + ((size_t)h * S_ + kb + r1) * HD_ + u * 8);
      short8 v0v = *(const short8*)(vht + ((size_t)h * HD_ + r0) * S_ + kb + u * 8);
      short8 v1v = *(const short8*)(vht + ((size_t)h * HD_ + r1) * S_ + kb + u * 8);
      *(short8*)(Ks + r0 * 128 + ((u ^ (r0 & 7)) << 4)) = k0v;
      *(short8*)(Ks + r1 * 128 + ((u ^ (r1 & 7)) << 4)) = k1v;
      *(short8*)(Vs + r0 * 128 + ((u ^ (r0 & 7)) << 4)) = v0v;
      *(short8*)(Vs + r1 * 128 + ((u ^ (r1 & 7)) << 4)) = v1v;
    }
    __syncthreads();
    // S^T tile
    f32x4 st[4];
#pragma unroll
    for (int kf = 0; kf < 4; ++kf) {
      int key = kf * 16 + lo;
      short8 a0 = *(const short8*)(Ks + key * 128 + ((g ^ (key & 7)) << 4));
      short8 a1 = *(const short8*)(Ks + key * 128 + (((4 + g) ^ (key & 7)) << 4));
      f32x4 z = (f32x4){0.f, 0.f, 0.f, 0.f};
      z = __builtin_amdgcn_mfma_f32_16x16x32_bf16(a0, bq0, z, 0, 0, 0);
      z = __builtin_amdgcn_mfma_f32_16x16x32_bf16(a1, bq1, z, 0, 0, 0);
      st[kf] = z;
    }
    // mask + online softmax (lane owns q = qw+lo, 16 key scores)
    float p[16];
    float tmax = -1e30f;
#pragma unroll
    for (int kf = 0; kf < 4; ++kf)
#pragma unroll
      for (int r = 0; r < 4; ++r) {
        int key = kb + kf * 16 + g * 4 + r;
        float s = st[kf][r] * 0.125f;
        bool okm = (key <= q) && (q - key < WIN_);
        s = okm ? s : -1e30f;
        p[kf * 4 + r] = s;
        tmax = fmaxf(tmax, s);
      }
    tmax = fmaxf(tmax, __shfl_xor(tmax, 16));
    tmax = fmaxf(tmax, __shfl_xor(tmax, 32));
    float m_new = fmaxf(m_run, tmax);
    float corr = __expf(m_run - m_new);
    float tsum = 0.f;
#pragma unroll
    for (int i = 0; i < 16; ++i) {
      float pe = (p[i] > -1e29f) ? __expf(p[i] - m_new) : 0.f;
      p[i] = pe;
      tsum += pe;
    }
    tsum += __shfl_xor(tsum, 16);
    tsum += __shfl_xor(tsum, 32);
    l_run = l_run * corr + tsum;
    m_run = m_new;
    // P -> bf16 LDS (per-wave region, swizzled)
#pragma unroll
    for (int kf = 0; kf < 4; ++kf)
#pragma unroll
      for (int pr = 0; pr < 2; ++pr) {
        int keyloc = kf * 16 + g * 4 + pr * 2;
        unsigned pk = (unsigned)f2bf(p[kf * 4 + pr * 2]) |
                      ((unsigned)f2bf(p[kf * 4 + pr * 2 + 1]) << 16);
        *(unsigned*)(Pw + lo * 128 + (((keyloc >> 3) ^ (lo & 7)) << 4) +
                     (keyloc & 7) * 2) = pk;
      }
    // rescale O rows by corr
    float c0 = __shfl(corr, g * 4 + 0), c1 = __shfl(corr, g * 4 + 1);
    float c2 = __shfl(corr, g * 4 + 2), c3 = __shfl(corr, g * 4 + 3);
#pragma unroll
    for (int nf = 0; nf < 4; ++nf) {
      o[nf][0] *= c0; o[nf][1] *= c1; o[nf][2] *= c2; o[nf][3] *= c3;
    }
    // PV
    short8 ap0 = *(const short8*)(Pw + lo * 128 + ((g ^ (lo & 7)) << 4));
    short8 ap1 = *(const short8*)(Pw + lo * 128 + (((4 + g) ^ (lo & 7)) << 4));
#pragma unroll
    for (int nf = 0; nf < 4; ++nf) {
      int d = nf * 16 + lo;
      short8 v0 = *(const short8*)(Vs + d * 128 + ((g ^ (d & 7)) << 4));
      short8 v1 = *(const short8*)(Vs + d * 128 + (((4 + g) ^ (d & 7)) << 4));
      o[nf] = __builtin_amdgcn_mfma_f32_16x16x32_bf16(ap0, v0, o[nf], 0, 0, 0);
      o[nf] = __builtin_amdgcn_mfma_f32_16x16x32_bf16(ap1, v1, o[nf], 0, 0, 0);
    }
    __syncthreads();
  }
  float linv = 1.f / l_run;
  float i0 = __shfl(linv, g * 4 + 0), i1 = __shfl(linv, g * 4 + 1);
  float i2 = __shfl(linv, g * 4 + 2), i3 = __shfl(linv, g * 4 + 3);
#pragma unroll
  for (int nf = 0; nf < 4; ++nf) {
    int d = nf * 16 + lo;
    attn[(size_t)(qw + g * 4 + 0) * HID_ + h * HD_ + d] = f2bf(o[nf][0] * i0);
    attn[(size_t)(qw + g * 4 + 1) * HID_ + h * HD_ + d] = f2bf(o[nf][1] * i1);
    attn[(size_t)(qw + g * 4 + 2) * HID_ + h * HD_ + d] = f2bf(o[nf][2] * i2);
    attn[(size_t)(qw + g * 4 + 3) * HID_ + h * HD_ + d] = f2bf(o[nf][3] * i3);
  }
}

// -------------------------------- combine -----------------------------------
__global__ __launch_bounds__(256) void combine_k(float* __restrict__ out,
                                                 const u16* __restrict__ eo,
                                                 const int* __restrict__ slot_of,
                                                 const float* __restrict__ topg) {
  int row = blockIdx.x, tid = threadIdx.x;
  int d0 = tid * 4;
  int p0 = slot_of[row * 2], p1 = slot_of[row * 2 + 1];
  float g0 = topg[row * 2], g1 = topg[row * 2 + 1];
  float4 cur = *(float4*)&out[(size_t)row * HID_ + d0];
  ushort4 ea = *(const ushort4*)&eo[(size_t)p0 * HID_ + d0];
  ushort4 eb = *(const ushort4*)&eo[(size_t)p1 * HID_ + d0];
  cur.x += g0 * bf2f(ea.x) + g1 * bf2f(eb.x);
  cur.y += g0 * bf2f(ea.y) + g1 * bf2f(eb.y);
  cur.z += g0 * bf2f(ea.z) + g1 * bf2f(eb.z);
  cur.w += g0 * bf2f(ea.w) + g1 * bf2f(eb.w);
  *(float4*)&out[(size_t)row * HID_ + d0] = cur;
}

// ------------------------------ host launcher -------------------------------
extern "C" void kernel_launch(void* const* d_in, const int* in_sizes, int n_in,
                              void* d_out, int out_size, void* d_ws,
                              size_t ws_size, hipStream_t stream) {
  const float* x = (const float*)d_in[0];
  const float* rot = (const float*)d_in[1];
  const float* r1w = (const float*)d_in[2];
  const float* wq = (const float*)d_in[3];
  const float* wk = (const float*)d_in[4];
  const float* wv = (const float*)d_in[5];
  const float* wo = (const float*)d_in[6];
  const float* r2w = (const float*)d_in[7];
  const float* gw = (const float*)d_in[8];
  const float* w1 = (const float*)d_in[9];
  const float* w2 = (const float*)d_in[10];
  const float* w3 = (const float*)d_in[11];
  float* out = (float*)d_out;

  char* ws = (char*)d_ws;
  size_t off = 0;
  auto alloc = [&](size_t bytes) {
    char* p = ws + off;
    off += (bytes + 255) & ~(size_t)255;
    return p;
  };
  u16* wqT = (u16*)alloc((size_t)HID_ * HID_ * 2);
  u16* wkT = (u16*)alloc((size_t)HID_ * HID_ * 2);
  u16* wvT = (u16*)alloc((size_t)HID_ * HID_ * 2);
  u16* woT = (u16*)alloc((size_t)HID_ * HID_ * 2);
  u16* w1T = (u16*)alloc((size_t)NE_ * DFF_ * HID_ * 2);
  u16* w3T = (u16*)alloc((size_t)NE_ * DFF_ * HID_ * 2);
  u16* w2T = (u16*)alloc((size_t)NE_ * HID_ * DFF_ * 2);
  u16* ybf = (u16*)alloc((size_t)S_ * HID_ * 2);
  u16* qh = (u16*)alloc((size_t)NH_ * S_ * HD_ * 2);
  u16* kh = (u16*)alloc((size_t)NH_ * S_ * HD_ * 2);
  u16* vh = (u16*)alloc((size_t)NH_ * S_ * HD_ * 2);
  u16* vht = (u16*)alloc((size_t)NH_ * S_ * HD_ * 2);
  u16* attn = (u16*)alloc((size_t)S_ * HID_ * 2);
  u16* y2bf = (u16*)alloc((size_t)S_ * HID_ * 2);
  u16* hbuf = (u16*)alloc((size_t)2 * S_ * DFF_ * 2);
  u16* eo = (u16*)alloc((size_t)2 * S_ * HID_ * 2);
  float* cost = (float*)alloc((size_t)S_ * 32 * 4);
  float* sint = (float*)alloc((size_t)S_ * 32 * 4);
  float* logits = (float*)alloc((size_t)S_ * NE_ * 4);
  int* topi = (int*)alloc((size_t)S_ * 2 * 4);
  float* topg = (float*)alloc((size_t)S_ * 2 * 4);
  int* ints = (int*)alloc(256);  // counts[8], rank[8], ebase[8]
  int* counts = ints;
  int* rank = ints + 8;
  int* ebase = ints + 16;
  int* slot_token = (int*)alloc((size_t)2 * S_ * 4);
  int* slot_of = (int*)alloc((size_t)S_ * 2 * 4);
  (void)ws_size; (void)in_sizes; (void)n_in; (void)out_size;

  hipMemsetAsync(counts, 0, 64, stream);  // counts + rank

  // weight conversions
  convT_f32_k<<<dim3(16, 16, 1), 256, 0, stream>>>(wq, wqT, HID_, HID_, (size_t)HID_ * HID_);
  convT_f32_k<<<dim3(16, 16, 1), 256, 0, stream>>>(wk, wkT, HID_, HID_, (size_t)HID_ * HID_);
  convT_f32_k<<<dim3(16, 16, 1), 256, 0, stream>>>(wv, wvT, HID_, HID_, (size_t)HID_ * HID_);
  convT_f32_k<<<dim3(16, 16, 1), 256, 0, stream>>>(wo, woT, HID_, HID_, (size_t)HID_ * HID_);
  convT_f32_k<<<dim3(64, 16, 8), 256, 0, stream>>>(w1, w1T, HID_, DFF_, (size_t)HID_ * DFF_);
  convT_f32_k<<<dim3(64, 16, 8), 256, 0, stream>>>(w3, w3T, HID_, DFF_, (size_t)HID_ * DFF_);
  convT_f32_k<<<dim3(16, 64, 8), 256, 0, stream>>>(w2, w2T, DFF_, HID_, (size_t)DFF_ * HID_);

  rope_tab_k<<<dim3(256), 256, 0, stream>>>(rot, cost, sint);
  rms1_k<<<dim3(S_), 256, 0, stream>>>(x, r1w, ybf);

  // QKV (+rope for q,k), head-major bf16 out
  gemm_k<0><<<dim3(16, 8, 3), 256, 0, stream>>>(ybf, wqT, wkT, wvT, HID_, nullptr,
                                                nullptr, nullptr, cost, sint,
                                                nullptr, nullptr, qh, kh, vh);
  convT_u16_k<<<dim3(1, 32, 16), 256, 0, stream>>>(vh, vht, S_, HD_, (size_t)S_ * HD_);

  attn_k<<<dim3(32, 16), 256, 0, stream>>>(qh, kh, vht, attn);

  // out-proj + residual -> d_out (x2)
  gemm_k<1><<<dim3(16, 8, 1), 256, 0, stream>>>(attn, woT, nullptr, nullptr, HID_,
                                                nullptr, nullptr, nullptr, nullptr,
                                                nullptr, x, out, nullptr, nullptr,
                                                nullptr);

  rms2_gate_k<<<dim3(S_), 256, 0, stream>>>(out, r2w, gw, y2bf, logits);
  topk_k<<<dim3(8), 256, 0, stream>>>(logits, topi, topg, counts);
  prefix_k<<<dim3(1), 64, 0, stream>>>(counts, ebase);
  scatter_k<<<dim3(8), 256, 0, stream>>>(topi, ebase, rank, slot_token, slot_of);

  // MoE grouped GEMMs
  gemm_k<2><<<dim3(16, 32, 8), 256, 0, stream>>>(y2bf, w1T, w3T, nullptr, HID_,
                                                 counts, ebase, slot_token, nullptr,
                                                 nullptr, nullptr, nullptr, hbuf,
                                                 nullptr, nullptr);
  gemm_k<3><<<dim3(16, 8, 8), 256, 0, stream>>>(hbuf, w2T, nullptr, nullptr, DFF_,
                                                counts, ebase, slot_token, nullptr,
                                                nullptr, nullptr, nullptr, eo,
                                                nullptr, nullptr);
  combine_k<<<dim3(S_), 256, 0, stream>>>(out, eo, slot_of, topg);
}

// Round 2
// 810.451 us; speedup vs baseline: 1.1553x; 1.1553x over previous
//
#include <hip/hip_runtime.h>
#include <hip/hip_bf16.h>
#include <stdint.h>

// ---------------------------------------------------------------------------
// TransformerBlock: rms1 -> QKV(+RoPE) -> window-512 flash attn -> out-proj(+x)
//                   -> rms2(+gate logits) -> top2 route -> grouped SwiGLU MoE -> +x2
// Round 2: GEMMs rebuilt on the m97 template: global_load_lds width-16 staging
// (linear LDS dest, inverse-swizzled global source), BK=32, 128^2 tile,
// double-buffered, 2-phase barrier loop. DUAL ffn1 split into w1/w3 blocks +
// separate swiglu fuse (register-pressure fix: ~264 -> ~170 regs/thread).
// ---------------------------------------------------------------------------

#define S_ 2048
#define HID_ 1024
#define NH_ 16
#define HD_ 64
#define WIN_ 512
#define DFF_ 4096
#define NE_ 8

typedef unsigned short u16;
typedef __attribute__((ext_vector_type(8))) short short8;
typedef __attribute__((ext_vector_type(4))) float f32x4;

__device__ __forceinline__ u16 f2bf(float f) {
  union { float f; unsigned u; } v; v.f = f;
  unsigned r = (v.u + 0x7FFFu + ((v.u >> 16) & 1u)) >> 16;
  return (u16)r;
}
__device__ __forceinline__ float bf2f(u16 b) {
  union { unsigned u; float f; } v; v.u = ((unsigned)b) << 16;
  return v.f;
}

// async global->LDS, 16B per lane. LDS dest must be wave-uniform base;
// HW writes base + lane*16 linearly. Global src is per-lane.
__device__ __forceinline__ void gload16(const void* g, void* l) {
  __builtin_amdgcn_global_load_lds(
      (const __attribute__((address_space(1))) void*)g,
      (__attribute__((address_space(3))) void*)l, 16, 0, 0);
}

// ------------------------- weight transpose+convert -------------------------
// W f32 [K][N]  ->  WT bf16 [N][K].  grid(N/64, K/64, nmat), 256 thr.
__global__ __launch_bounds__(256) void convT_f32_k(const float* __restrict__ W,
                                                   u16* __restrict__ WT,
                                                   int K, int N, size_t matStride) {
  __shared__ u16 t[64][66];
  const float* Wm = W + (size_t)blockIdx.z * matStride;
  u16* WTm = WT + (size_t)blockIdx.z * matStride;
  int n0 = blockIdx.x * 64, k0 = blockIdx.y * 64;
  int tid = threadIdx.x;
  int c2 = (tid & 31) * 2, rr = tid >> 5;
#pragma unroll
  for (int it = 0; it < 8; ++it) {
    int r = it * 8 + rr;
    float2 ab = *(const float2*)&Wm[(size_t)(k0 + r) * N + n0 + c2];
    t[c2][r] = f2bf(ab.x);
    t[c2 + 1][r] = f2bf(ab.y);
  }
  __syncthreads();
#pragma unroll
  for (int it = 0; it < 8; ++it) {
    int n = it * 8 + rr;
    unsigned pk = (unsigned)t[n][c2] | ((unsigned)t[n][c2 + 1] << 16);
    *(unsigned*)&WTm[(size_t)(n0 + n) * K + k0 + c2] = pk;
  }
}

// bf16 [K][N] -> bf16 [N][K] (for V: [s][d] -> [d][s] per head)
__global__ __launch_bounds__(256) void convT_u16_k(const u16* __restrict__ W,
                                                   u16* __restrict__ WT,
                                                   int K, int N, size_t matStride) {
  __shared__ u16 t[64][66];
  const u16* Wm = W + (size_t)blockIdx.z * matStride;
  u16* WTm = WT + (size_t)blockIdx.z * matStride;
  int n0 = blockIdx.x * 64, k0 = blockIdx.y * 64;
  int tid = threadIdx.x;
  int c2 = (tid & 31) * 2, rr = tid >> 5;
#pragma unroll
  for (int it = 0; it < 8; ++it) {
    int r = it * 8 + rr;
    unsigned vv = *(const unsigned*)&Wm[(size_t)(k0 + r) * N + n0 + c2];
    t[c2][r] = (u16)vv;
    t[c2 + 1][r] = (u16)(vv >> 16);
  }
  __syncthreads();
#pragma unroll
  for (int it = 0; it < 8; ++it) {
    int n = it * 8 + rr;
    unsigned pk = (unsigned)t[n][c2] | ((unsigned)t[n][c2 + 1] << 16);
    *(unsigned*)&WTm[(size_t)(n0 + n) * K + k0 + c2] = pk;
  }
}

// ------------------------------- rope tables --------------------------------
__global__ __launch_bounds__(256) void rope_tab_k(const float* __restrict__ rot,
                                                  float* __restrict__ cost,
                                                  float* __restrict__ sint) {
  int id = blockIdx.x * 256 + threadIdx.x;
  if (id >= S_ * 32) return;
  int s = id >> 5, j = id & 31;
  cost[id] = rot[(size_t)s * 4096 + (size_t)(2 * j) * 64 + 2 * j];
  sint[id] = rot[(size_t)s * 4096 + (size_t)(2 * j + 1) * 64 + 2 * j];
}

// --------------------------------- rmsnorm 1 --------------------------------
__global__ __launch_bounds__(256) void rms1_k(const float* __restrict__ x,
                                              const float* __restrict__ rw,
                                              u16* __restrict__ y) {
  int row = blockIdx.x, tid = threadIdx.x;
  const float4 v = *(const float4*)&x[(size_t)row * HID_ + tid * 4];
  float ss = v.x * v.x + v.y * v.y + v.z * v.z + v.w * v.w;
#pragma unroll
  for (int o = 32; o; o >>= 1) ss += __shfl_xor(ss, o);
  __shared__ float red[4];
  if ((tid & 63) == 0) red[tid >> 6] = ss;
  __syncthreads();
  float rstd = rsqrtf((red[0] + red[1] + red[2] + red[3]) * (1.f / HID_) + 1e-6f);
  const float4 w4 = *(const float4*)&rw[tid * 4];
  ushort4 o4;
  o4.x = f2bf(v.x * rstd * w4.x);
  o4.y = f2bf(v.y * rstd * w4.y);
  o4.z = f2bf(v.z * rstd * w4.z);
  o4.w = f2bf(v.w * rstd * w4.w);
  *(ushort4*)&y[(size_t)row * HID_ + tid * 4] = o4;
}

// ------------------------- rmsnorm 2 + gate logits --------------------------
__global__ __launch_bounds__(256) void rms2_gate_k(const float* __restrict__ x2,
                                                   const float* __restrict__ rw,
                                                   const float* __restrict__ gw,
                                                   u16* __restrict__ y2,
                                                   float* __restrict__ logits) {
  int row = blockIdx.x, tid = threadIdx.x;
  int wv = tid >> 6, ln = tid & 63;
  const float4 v = *(const float4*)&x2[(size_t)row * HID_ + tid * 4];
  float ss = v.x * v.x + v.y * v.y + v.z * v.z + v.w * v.w;
#pragma unroll
  for (int o = 32; o; o >>= 1) ss += __shfl_xor(ss, o);
  __shared__ float red[4];
  __shared__ float lred[4][8];
  if (ln == 0) red[wv] = ss;
  __syncthreads();
  float rstd = rsqrtf((red[0] + red[1] + red[2] + red[3]) * (1.f / HID_) + 1e-6f);
  const float4 w4 = *(const float4*)&rw[tid * 4];
  float yv[4];
  yv[0] = v.x * rstd * w4.x; yv[1] = v.y * rstd * w4.y;
  yv[2] = v.z * rstd * w4.z; yv[3] = v.w * rstd * w4.w;
  ushort4 o4;
  o4.x = f2bf(yv[0]); o4.y = f2bf(yv[1]); o4.z = f2bf(yv[2]); o4.w = f2bf(yv[3]);
  *(ushort4*)&y2[(size_t)row * HID_ + tid * 4] = o4;
  float le[8] = {0, 0, 0, 0, 0, 0, 0, 0};
  int d0 = tid * 4;
#pragma unroll
  for (int j = 0; j < 4; ++j) {
    const float* grow = &gw[(size_t)(d0 + j) * NE_];
#pragma unroll
    for (int e = 0; e < 8; ++e) le[e] += yv[j] * grow[e];
  }
#pragma unroll
  for (int e = 0; e < 8; ++e) {
    float t = le[e];
#pragma unroll
    for (int o = 32; o; o >>= 1) t += __shfl_xor(t, o);
    le[e] = t;
  }
  if (ln == 0)
#pragma unroll
    for (int e = 0; e < 8; ++e) lred[wv][e] = le[e];
  __syncthreads();
  if (tid < 8)
    logits[(size_t)row * NE_ + tid] =
        lred[0][tid] + lred[1][tid] + lred[2][tid] + lred[3][tid];
}

// ------------------------------ top-2 routing -------------------------------
__global__ __launch_bounds__(256) void topk_k(const float* __restrict__ logits,
                                              int* __restrict__ topi,
                                              float* __restrict__ topg,
                                              int* __restrict__ counts) {
  int t = blockIdx.x * 256 + threadIdx.x;
  if (t >= S_) return;
  const float* lg = &logits[(size_t)t * NE_];
  float v0 = -1e30f; int i0 = 0;
#pragma unroll
  for (int e = 0; e < 8; ++e) {
    float x = lg[e];
    if (x > v0) { v0 = x; i0 = e; }
  }
  float v1 = -1e30f; int i1 = 0;
#pragma unroll
  for (int e = 0; e < 8; ++e) {
    if (e == i0) continue;
    float x = lg[e];
    if (x > v1) { v1 = x; i1 = e; }
  }
  float e1 = __expf(v1 - v0);
  topi[t * 2] = i0; topi[t * 2 + 1] = i1;
  topg[t * 2] = 1.f / (1.f + e1);
  topg[t * 2 + 1] = e1 / (1.f + e1);
  atomicAdd(&counts[i0], 1);
  atomicAdd(&counts[i1], 1);
}

__global__ void prefix_k(const int* __restrict__ counts, int* __restrict__ ebase) {
  if (threadIdx.x == 0) {
    int s = 0;
    for (int e = 0; e < 8; ++e) { ebase[e] = s; s += counts[e]; }
  }
}

__global__ __launch_bounds__(256) void scatter_k(const int* __restrict__ topi,
                                                 const int* __restrict__ ebase,
                                                 int* __restrict__ rank,
                                                 int* __restrict__ slot_token,
                                                 int* __restrict__ slot_of) {
  int t = blockIdx.x * 256 + threadIdx.x;
  if (t >= S_) return;
  for (int k = 0; k < 2; ++k) {
    int e = topi[t * 2 + k];
    int pos = ebase[e] + atomicAdd(&rank[e], 1);
    slot_token[pos] = t;
    slot_of[t * 2 + k] = pos;
  }
}

// --------------------------------- GEMM -------------------------------------
// m97 template: 128x128 tile, BK=32, 4 waves (64x64 each = 4x4 frags),
// double-buffered LDS (32 KiB), global_load_lds width-16 staging with
// inverse-swizzled global source (swz: unit ^= (row>>1)&3), 2-phase loop.
// MODE 0: qkv (z picks wq/wk/wv; rope for z<2; out head-major bf16)
// MODE 1: out-proj (+x residual, f32 out)
// MODE 2: ffn1 single-B (z = e*2+mat; mat 0 -> w1/h1, 1 -> w3/h3; gathered A)
// MODE 3: ffn2 (compact rows, out eo bf16 [slot][1024])
template <int MODE>
__global__ __launch_bounds__(256) void gemm_k(
    const u16* __restrict__ A, const u16* __restrict__ B0,
    const u16* __restrict__ B1, const u16* __restrict__ B2, int K,
    const int* __restrict__ ecnt, const int* __restrict__ ebase,
    const int* __restrict__ slot_token, const float* __restrict__ cost,
    const float* __restrict__ sint, const float* __restrict__ xres,
    float* __restrict__ outf, u16* __restrict__ o0, u16* __restrict__ o1,
    u16* __restrict__ o2) {
  __shared__ alignas(16) char smem[32768];
  char* As = smem;
  char* Bs = smem + 16384;

  int m0 = blockIdx.x * 128, n0 = blockIdx.y * 128;
  int cnt = 0, base = 0;
  const u16* Bp;
  u16* outb = o0;
  int rope = 0;
  if constexpr (MODE == 0) {
    int z = blockIdx.z;
    Bp = (z == 0) ? B0 : (z == 1) ? B1 : B2;
    outb = (z == 0) ? o0 : (z == 1) ? o1 : o2;
    rope = (z < 2) ? 1 : 0;
  } else if constexpr (MODE == 1) {
    Bp = B0;
  } else if constexpr (MODE == 2) {
    int e = blockIdx.z >> 1, mat = blockIdx.z & 1;
    cnt = ecnt[e]; base = ebase[e];
    if (m0 >= cnt) return;
    Bp = (mat ? B1 : B0) + (size_t)e * DFF_ * HID_;
    outb = mat ? o1 : o0;
  } else {
    int e = blockIdx.z;
    cnt = ecnt[e]; base = ebase[e];
    if (m0 >= cnt) return;
    Bp = B0 + (size_t)e * HID_ * DFF_;
  }

  int tid = threadIdx.x, w = tid >> 6, l = tid & 63, lo = l & 15, g = l >> 4;
  int wm = w & 1, wn = w >> 1;
  int KT = K >> 5;

  // staging: lane covers tile rows r0 and r0+16, 16B unit u=l&3.
  // LDS dest linear (HW: wave base + lane*16); source column pre-swizzled.
  int r0 = w * 32 + (l >> 2);
  int r1 = r0 + 16;
  int u = l & 3;
  int sw0 = (u ^ ((r0 >> 1) & 3)) << 4;
  int sw1 = (u ^ ((r1 >> 1) & 3)) << 4;

  const char *pA0, *pA1;
  if constexpr (MODE == 2) {
    int t0 = slot_token[base + min(m0 + r0, cnt - 1)];
    int t1 = slot_token[base + min(m0 + r1, cnt - 1)];
    pA0 = (const char*)(A + (size_t)t0 * K) + sw0;
    pA1 = (const char*)(A + (size_t)t1 * K) + sw1;
  } else if constexpr (MODE == 3) {
    pA0 = (const char*)(A + (size_t)(base + min(m0 + r0, cnt - 1)) * K) + sw0;
    pA1 = (const char*)(A + (size_t)(base + min(m0 + r1, cnt - 1)) * K) + sw1;
  } else {
    pA0 = (const char*)(A + (size_t)(m0 + r0) * K) + sw0;
    pA1 = (const char*)(A + (size_t)(m0 + r1) * K) + sw1;
  }
  const char* pB0 = (const char*)(Bp + (size_t)(n0 + r0) * K) + sw0;
  const char* pB1 = (const char*)(Bp + (size_t)(n0 + r1) * K) + sw1;

  char* ldA0 = As + (w * 2 + 0) * 1024;
  char* ldA1 = As + (w * 2 + 1) * 1024;
  char* ldB0 = Bs + (w * 2 + 0) * 1024;
  char* ldB1 = Bs + (w * 2 + 1) * 1024;

  f32x4 acc[4][4];
#pragma unroll
  for (int i = 0; i < 4; ++i)
#pragma unroll
    for (int j = 0; j < 4; ++j) acc[i][j] = (f32x4){0.f, 0.f, 0.f, 0.f};

  // prologue: stage K-step 0 into buf 0
  gload16(pA0, ldA0); gload16(pA1, ldA1);
  gload16(pB0, ldB0); gload16(pB1, ldB1);
  __syncthreads();

  for (int kt = 0; kt < KT; ++kt) {
    int cur = kt & 1;
    if (kt + 1 < KT) {  // stage next K-step first (T3: issue before ds_read)
      size_t kb = (size_t)(kt + 1) * 64;
      int nb = (cur ^ 1) * 8192;
      gload16(pA0 + kb, ldA0 + nb); gload16(pA1 + kb, ldA1 + nb);
      gload16(pB0 + kb, ldB0 + nb); gload16(pB1 + kb, ldB1 + nb);
    }
    short8 af[4], bf_[4];
#pragma unroll
    for (int mi = 0; mi < 4; ++mi) {
      int r = wm * 64 + mi * 16 + lo;
      af[mi] = *(const short8*)(As + cur * 8192 + r * 64 + ((g ^ ((r >> 1) & 3)) << 4));
    }
#pragma unroll
    for (int ni = 0; ni < 4; ++ni) {
      int r = wn * 64 + ni * 16 + lo;
      bf_[ni] = *(const short8*)(Bs + cur * 8192 + r * 64 + ((g ^ ((r >> 1) & 3)) << 4));
    }
#pragma unroll
    for (int mi = 0; mi < 4; ++mi)
#pragma unroll
      for (int ni = 0; ni < 4; ++ni)
        acc[mi][ni] = __builtin_amdgcn_mfma_f32_16x16x32_bf16(af[mi], bf_[ni], acc[mi][ni], 0, 0, 0);
    __syncthreads();  // drains vmcnt(0): next buffer staged, this one free
  }

  // epilogue
#pragma unroll
  for (int mi = 0; mi < 4; ++mi) {
    int lr = wm * 64 + mi * 16 + g * 4;
#pragma unroll
    for (int ni = 0; ni < 4; ++ni) {
      int c = n0 + wn * 64 + ni * 16 + lo;
#pragma unroll
      for (int r = 0; r < 4; ++r) {
        float v = acc[mi][ni][r];
        if constexpr (MODE == 0) {
          int row = m0 + lr + r;
          float p = __shfl_xor(v, 1);
          if (rope) {
            int dd = c & 63;
            float co = cost[(size_t)row * 32 + (dd >> 1)];
            float si = sint[(size_t)row * 32 + (dd >> 1)];
            v = (dd & 1) ? (co * v - si * p) : (co * v + si * p);
          }
          outb[((size_t)(c >> 6) * S_ + row) * HD_ + (c & 63)] = f2bf(v);
        } else if constexpr (MODE == 1) {
          int row = m0 + lr + r;
          outf[(size_t)row * HID_ + c] = v + xres[(size_t)row * HID_ + c];
        } else if constexpr (MODE == 2) {
          int m = m0 + lr + r;
          if (m < cnt) outb[(size_t)(base + m) * DFF_ + c] = f2bf(v);
        } else {
          int m = m0 + lr + r;
          if (m < cnt) outb[(size_t)(base + m) * HID_ + c] = f2bf(v);
        }
      }
    }
  }
}

// ----------------------------- swiglu fuse ----------------------------------
// h1 <- silu(h1) * h3, elementwise over [4096][DFF] bf16.
__global__ __launch_bounds__(256) void swiglu_k(u16* __restrict__ h1,
                                                const u16* __restrict__ h3) {
  size_t i = ((size_t)blockIdx.x * 256 + threadIdx.x) * 8;
  short8 a = *(const short8*)(h1 + i);
  short8 b = *(const short8*)(h3 + i);
  short8 o;
#pragma unroll
  for (int j = 0; j < 8; ++j) {
    float x = bf2f((u16)a[j]), y = bf2f((u16)b[j]);
    float s = x / (1.f + __expf(-x));
    o[j] = (short)f2bf(s * y);
  }
  *(short8*)(h1 + i) = o;
}

// ------------------------------- attention ----------------------------------
__global__ __launch_bounds__(256) void attn_k(const u16* __restrict__ qh,
                                              const u16* __restrict__ kh,
                                              const u16* __restrict__ vht,
                                              u16* __restrict__ attn) {
  int qt = blockIdx.x, h = blockIdx.y;
  int tid = threadIdx.x, w = tid >> 6, l = tid & 63, lo = l & 15, g = l >> 4;
  __shared__ alignas(16) char Ks[8192];
  __shared__ alignas(16) char Vs[8192];
  __shared__ alignas(16) char Ps[8192];
  char* Pw = Ps + w * 2048;
  int q0 = qt * 64, qw = q0 + w * 16;
  const u16* qhh = qh + ((size_t)h * S_ + qw) * HD_;
  short8 bq0 = *(const short8*)(qhh + lo * 64 + g * 8);
  short8 bq1 = *(const short8*)(qhh + lo * 64 + 32 + g * 8);
  int q = qw + lo;
  float m_run = -1e30f, l_run = 0.f;
  f32x4 o[4];
#pragma unroll
  for (int i = 0; i < 4; ++i) o[i] = (f32x4){0.f, 0.f, 0.f, 0.f};
  int kt0 = max(0, q0 - (WIN_ - 1)) >> 6;
  for (int kt = kt0; kt <= qt; ++kt) {
    int kb = kt * 64;
    {
      int r0 = w * 16 + (l >> 3), r1 = r0 + 8;
      int uu = l & 7;
      short8 k0v = *(const short8*)(kh + ((size_t)h * S_ + kb + r0) * HD_ + uu * 8);
      short8 k1v = *(const short8*)(kh + ((size_t)h * S_ + kb + r1) * HD_ + uu * 8);
      short8 v0v = *(const short8*)(vht + ((size_t)h * HD_ + r0) * S_ + kb + uu * 8);
      short8 v1v = *(const short8*)(vht + ((size_t)h * HD_ + r1) * S_ + kb + uu * 8);
      *(short8*)(Ks + r0 * 128 + ((uu ^ (r0 & 7)) << 4)) = k0v;
      *(short8*)(Ks + r1 * 128 + ((uu ^ (r1 & 7)) << 4)) = k1v;
      *(short8*)(Vs + r0 * 128 + ((uu ^ (r0 & 7)) << 4)) = v0v;
      *(short8*)(Vs + r1 * 128 + ((uu ^ (r1 & 7)) << 4)) = v1v;
    }
    __syncthreads();
    f32x4 st[4];
#pragma unroll
    for (int kf = 0; kf < 4; ++kf) {
      int key = kf * 16 + lo;
      short8 a0 = *(const short8*)(Ks + key * 128 + ((g ^ (key & 7)) << 4));
      short8 a1 = *(const short8*)(Ks + key * 128 + (((4 + g) ^ (key & 7)) << 4));
      f32x4 z = (f32x4){0.f, 0.f, 0.f, 0.f};
      z = __builtin_amdgcn_mfma_f32_16x16x32_bf16(a0, bq0, z, 0, 0, 0);
      z = __builtin_amdgcn_mfma_f32_16x16x32_bf16(a1, bq1, z, 0, 0, 0);
      st[kf] = z;
    }
    float p[16];
    float tmax = -1e30f;
#pragma unroll
    for (int kf = 0; kf < 4; ++kf)
#pragma unroll
      for (int r = 0; r < 4; ++r) {
        int key = kb + kf * 16 + g * 4 + r;
        float s = st[kf][r] * 0.125f;
        bool okm = (key <= q) && (q - key < WIN_);
        s = okm ? s : -1e30f;
        p[kf * 4 + r] = s;
        tmax = fmaxf(tmax, s);
      }
    tmax = fmaxf(tmax, __shfl_xor(tmax, 16));
    tmax = fmaxf(tmax, __shfl_xor(tmax, 32));
    float m_new = fmaxf(m_run, tmax);
    float corr = __expf(m_run - m_new);
    float tsum = 0.f;
#pragma unroll
    for (int i = 0; i < 16; ++i) {
      float pe = (p[i] > -1e29f) ? __expf(p[i] - m_new) : 0.f;
      p[i] = pe;
      tsum += pe;
    }
    tsum += __shfl_xor(tsum, 16);
    tsum += __shfl_xor(tsum, 32);
    l_run = l_run * corr + tsum;
    m_run = m_new;
#pragma unroll
    for (int kf = 0; kf < 4; ++kf)
#pragma unroll
      for (int pr = 0; pr < 2; ++pr) {
        int keyloc = kf * 16 + g * 4 + pr * 2;
        unsigned pk = (unsigned)f2bf(p[kf * 4 + pr * 2]) |
                      ((unsigned)f2bf(p[kf * 4 + pr * 2 + 1]) << 16);
        *(unsigned*)(Pw + lo * 128 + (((keyloc >> 3) ^ (lo & 7)) << 4) +
                     (keyloc & 7) * 2) = pk;
      }
    float c0 = __shfl(corr, g * 4 + 0), c1 = __shfl(corr, g * 4 + 1);
    float c2 = __shfl(corr, g * 4 + 2), c3 = __shfl(corr, g * 4 + 3);
#pragma unroll
    for (int nf = 0; nf < 4; ++nf) {
      o[nf][0] *= c0; o[nf][1] *= c1; o[nf][2] *= c2; o[nf][3] *= c3;
    }
    short8 ap0 = *(const short8*)(Pw + lo * 128 + ((g ^ (lo & 7)) << 4));
    short8 ap1 = *(const short8*)(Pw + lo * 128 + (((4 + g) ^ (lo & 7)) << 4));
#pragma unroll
    for (int nf = 0; nf < 4; ++nf) {
      int d = nf * 16 + lo;
      short8 v0 = *(const short8*)(Vs + d * 128 + ((g ^ (d & 7)) << 4));
      short8 v1 = *(const short8*)(Vs + d * 128 + (((4 + g) ^ (d & 7)) << 4));
      o[nf] = __builtin_amdgcn_mfma_f32_16x16x32_bf16(ap0, v0, o[nf], 0, 0, 0);
      o[nf] = __builtin_amdgcn_mfma_f32_16x16x32_bf16(ap1, v1, o[nf], 0, 0, 0);
    }
    __syncthreads();
  }
  float linv = 1.f / l_run;
  float i0 = __shfl(linv, g * 4 + 0), i1 = __shfl(linv, g * 4 + 1);
  float i2 = __shfl(linv, g * 4 + 2), i3 = __shfl(linv, g * 4 + 3);
#pragma unroll
  for (int nf = 0; nf < 4; ++nf) {
    int d = nf * 16 + lo;
    attn[(size_t)(qw + g * 4 + 0) * HID_ + h * HD_ + d] = f2bf(o[nf][0] * i0);
    attn[(size_t)(qw + g * 4 + 1) * HID_ + h * HD_ + d] = f2bf(o[nf][1] * i1);
    attn[(size_t)(qw + g * 4 + 2) * HID_ + h * HD_ + d] = f2bf(o[nf][2] * i2);
    attn[(size_t)(qw + g * 4 + 3) * HID_ + h * HD_ + d] = f2bf(o[nf][3] * i3);
  }
}

// -------------------------------- combine -----------------------------------
__global__ __launch_bounds__(256) void combine_k(float* __restrict__ out,
                                                 const u16* __restrict__ eo,
                                                 const int* __restrict__ slot_of,
                                                 const float* __restrict__ topg) {
  int row = blockIdx.x, tid = threadIdx.x;
  int d0 = tid * 4;
  int p0 = slot_of[row * 2], p1 = slot_of[row * 2 + 1];
  float g0 = topg[row * 2], g1 = topg[row * 2 + 1];
  float4 cur = *(float4*)&out[(size_t)row * HID_ + d0];
  ushort4 ea = *(const ushort4*)&eo[(size_t)p0 * HID_ + d0];
  ushort4 eb = *(const ushort4*)&eo[(size_t)p1 * HID_ + d0];
  cur.x += g0 * bf2f(ea.x) + g1 * bf2f(eb.x);
  cur.y += g0 * bf2f(ea.y) + g1 * bf2f(eb.y);
  cur.z += g0 * bf2f(ea.z) + g1 * bf2f(eb.z);
  cur.w += g0 * bf2f(ea.w) + g1 * bf2f(eb.w);
  *(float4*)&out[(size_t)row * HID_ + d0] = cur;
}

// ------------------------------ host launcher -------------------------------
extern "C" void kernel_launch(void* const* d_in, const int* in_sizes, int n_in,
                              void* d_out, int out_size, void* d_ws,
                              size_t ws_size, hipStream_t stream) {
  const float* x = (const float*)d_in[0];
  const float* rot = (const float*)d_in[1];
  const float* r1w = (const float*)d_in[2];
  const float* wq = (const float*)d_in[3];
  const float* wk = (const float*)d_in[4];
  const float* wv = (const float*)d_in[5];
  const float* wo = (const float*)d_in[6];
  const float* r2w = (const float*)d_in[7];
  const float* gw = (const float*)d_in[8];
  const float* w1 = (const float*)d_in[9];
  const float* w2 = (const float*)d_in[10];
  const float* w3 = (const float*)d_in[11];
  float* out = (float*)d_out;

  char* ws = (char*)d_ws;
  size_t off = 0;
  auto alloc = [&](size_t bytes) {
    char* p = ws + off;
    off += (bytes + 255) & ~(size_t)255;
    return p;
  };
  const size_t MB4 = (size_t)S_ * HID_ * 2;  // 4 MiB
  u16* wqT = (u16*)alloc((size_t)HID_ * HID_ * 2);
  u16* wkT = (u16*)alloc((size_t)HID_ * HID_ * 2);
  u16* wvT = (u16*)alloc((size_t)HID_ * HID_ * 2);
  u16* woT = (u16*)alloc((size_t)HID_ * HID_ * 2);
  u16* w1T = (u16*)alloc((size_t)NE_ * DFF_ * HID_ * 2);
  u16* w3T = (u16*)alloc((size_t)NE_ * DFF_ * HID_ * 2);
  u16* w2T = (u16*)alloc((size_t)NE_ * HID_ * DFF_ * 2);
  // union block: attn-phase temporaries, later reused as h3 (32 MiB)
  char* uni = alloc((size_t)2 * S_ * DFF_ * 2);
  u16* ybf = (u16*)(uni);
  u16* qh = (u16*)(uni + MB4);
  u16* kh = (u16*)(uni + 2 * MB4);
  u16* vh = (u16*)(uni + 3 * MB4);
  u16* vht = (u16*)(uni + 4 * MB4);
  u16* attnb = (u16*)(uni + 5 * MB4);
  u16* h3 = (u16*)uni;  // alive only after attn phase
  u16* y2bf = (u16*)alloc(MB4);
  u16* h1 = (u16*)alloc((size_t)2 * S_ * DFF_ * 2);
  u16* eo = (u16*)alloc((size_t)2 * S_ * HID_ * 2);
  float* cost = (float*)alloc((size_t)S_ * 32 * 4);
  float* sint = (float*)alloc((size_t)S_ * 32 * 4);
  float* logits = (float*)alloc((size_t)S_ * NE_ * 4);
  int* topi = (int*)alloc((size_t)S_ * 2 * 4);
  float* topg = (float*)alloc((size_t)S_ * 2 * 4);
  int* ints = (int*)alloc(256);  // counts[8], rank[8], ebase[8]
  int* counts = ints;
  int* rank = ints + 8;
  int* ebase = ints + 16;
  int* slot_token = (int*)alloc((size_t)2 * S_ * 4);
  int* slot_of = (int*)alloc((size_t)S_ * 2 * 4);
  (void)ws_size; (void)in_sizes; (void)n_in; (void)out_size;

  hipMemsetAsync(counts, 0, 64, stream);  // counts + rank

  convT_f32_k<<<dim3(16, 16, 1), 256, 0, stream>>>(wq, wqT, HID_, HID_, (size_t)HID_ * HID_);
  convT_f32_k<<<dim3(16, 16, 1), 256, 0, stream>>>(wk, wkT, HID_, HID_, (size_t)HID_ * HID_);
  convT_f32_k<<<dim3(16, 16, 1), 256, 0, stream>>>(wv, wvT, HID_, HID_, (size_t)HID_ * HID_);
  convT_f32_k<<<dim3(16, 16, 1), 256, 0, stream>>>(wo, woT, HID_, HID_, (size_t)HID_ * HID_);
  convT_f32_k<<<dim3(64, 16, 8), 256, 0, stream>>>(w1, w1T, HID_, DFF_, (size_t)HID_ * DFF_);
  convT_f32_k<<<dim3(64, 16, 8), 256, 0, stream>>>(w3, w3T, HID_, DFF_, (size_t)HID_ * DFF_);
  convT_f32_k<<<dim3(16, 64, 8), 256, 0, stream>>>(w2, w2T, DFF_, HID_, (size_t)DFF_ * HID_);

  rope_tab_k<<<dim3(256), 256, 0, stream>>>(rot, cost, sint);
  rms1_k<<<dim3(S_), 256, 0, stream>>>(x, r1w, ybf);

  gemm_k<0><<<dim3(16, 8, 3), 256, 0, stream>>>(ybf, wqT, wkT, wvT, HID_, nullptr,
                                                nullptr, nullptr, cost, sint,
                                                nullptr, nullptr, qh, kh, vh);
  convT_u16_k<<<dim3(1, 32, 16), 256, 0, stream>>>(vh, vht, S_, HD_, (size_t)S_ * HD_);

  attn_k<<<dim3(32, 16), 256, 0, stream>>>(qh, kh, vht, attnb);

  gemm_k<1><<<dim3(16, 8, 1), 256, 0, stream>>>(attnb, woT, nullptr, nullptr, HID_,
                                                nullptr, nullptr, nullptr, nullptr,
                                                nullptr, x, out, nullptr, nullptr,
                                                nullptr);

  rms2_gate_k<<<dim3(S_), 256, 0, stream>>>(out, r2w, gw, y2bf, logits);
  topk_k<<<dim3(8), 256, 0, stream>>>(logits, topi, topg, counts);
  prefix_k<<<dim3(1), 64, 0, stream>>>(counts, ebase);
  scatter_k<<<dim3(8), 256, 0, stream>>>(topi, ebase, rank, slot_token, slot_of);

  // ffn1: z = e*2 + mat  (mat 0 -> w1/h1, 1 -> w3/h3)
  gemm_k<2><<<dim3(16, 32, 16), 256, 0, stream>>>(y2bf, w1T, w3T, nullptr, HID_,
                                                  counts, ebase, slot_token, nullptr,
                                                  nullptr, nullptr, nullptr, h1, h3,
                                                  nullptr);
  swiglu_k<<<dim3(8192), 256, 0, stream>>>(h1, h3);
  gemm_k<3><<<dim3(16, 8, 8), 256, 0, stream>>>(h1, w2T, nullptr, nullptr, DFF_,
                                                counts, ebase, slot_token, nullptr,
                                                nullptr, nullptr, nullptr, eo,
                                                nullptr, nullptr);
  combine_k<<<dim3(S_), 256, 0, stream>>>(out, eo, slot_of, topg);
}

// Round 3
// 766.833 us; speedup vs baseline: 1.2210x; 1.0569x over previous
//
#include <hip/hip_runtime.h>
#include <hip/hip_bf16.h>
#include <stdint.h>

// ---------------------------------------------------------------------------
// TransformerBlock: rms1 -> QKV(+RoPE) -> window-512 flash attn -> out-proj(+x)
//                   -> rms2(+gate logits) -> top2 route -> grouped SwiGLU MoE -> +x2
// Round 3: GEMM K-loop rebuilt as T3+T4 pipeline: 3 LDS buffers, raw s_barrier,
// counted s_waitcnt vmcnt(4) (never 0 in-loop) so global_load_lds prefetch
// survives barriers. One barrier per K-step.
// ---------------------------------------------------------------------------

#define S_ 2048
#define HID_ 1024
#define NH_ 16
#define HD_ 64
#define WIN_ 512
#define DFF_ 4096
#define NE_ 8

typedef unsigned short u16;
typedef __attribute__((ext_vector_type(8))) short short8;
typedef __attribute__((ext_vector_type(4))) float f32x4;

__device__ __forceinline__ u16 f2bf(float f) {
  union { float f; unsigned u; } v; v.f = f;
  unsigned r = (v.u + 0x7FFFu + ((v.u >> 16) & 1u)) >> 16;
  return (u16)r;
}
__device__ __forceinline__ float bf2f(u16 b) {
  union { unsigned u; float f; } v; v.u = ((unsigned)b) << 16;
  return v.f;
}

// async global->LDS, 16B per lane. LDS dest wave-uniform base + lane*16.
__device__ __forceinline__ void gload16(const void* g, void* l) {
  __builtin_amdgcn_global_load_lds(
      (const __attribute__((address_space(1))) void*)g,
      (__attribute__((address_space(3))) void*)l, 16, 0, 0);
}

// ------------------------- weight transpose+convert -------------------------
__global__ __launch_bounds__(256) void convT_f32_k(const float* __restrict__ W,
                                                   u16* __restrict__ WT,
                                                   int K, int N, size_t matStride) {
  __shared__ u16 t[64][66];
  const float* Wm = W + (size_t)blockIdx.z * matStride;
  u16* WTm = WT + (size_t)blockIdx.z * matStride;
  int n0 = blockIdx.x * 64, k0 = blockIdx.y * 64;
  int tid = threadIdx.x;
  int c2 = (tid & 31) * 2, rr = tid >> 5;
#pragma unroll
  for (int it = 0; it < 8; ++it) {
    int r = it * 8 + rr;
    float2 ab = *(const float2*)&Wm[(size_t)(k0 + r) * N + n0 + c2];
    t[c2][r] = f2bf(ab.x);
    t[c2 + 1][r] = f2bf(ab.y);
  }
  __syncthreads();
#pragma unroll
  for (int it = 0; it < 8; ++it) {
    int n = it * 8 + rr;
    unsigned pk = (unsigned)t[n][c2] | ((unsigned)t[n][c2 + 1] << 16);
    *(unsigned*)&WTm[(size_t)(n0 + n) * K + k0 + c2] = pk;
  }
}

// bf16 [K][N] -> bf16 [N][K] (for V: [s][d] -> [d][s] per head)
__global__ __launch_bounds__(256) void convT_u16_k(const u16* __restrict__ W,
                                                   u16* __restrict__ WT,
                                                   int K, int N, size_t matStride) {
  __shared__ u16 t[64][66];
  const u16* Wm = W + (size_t)blockIdx.z * matStride;
  u16* WTm = WT + (size_t)blockIdx.z * matStride;
  int n0 = blockIdx.x * 64, k0 = blockIdx.y * 64;
  int tid = threadIdx.x;
  int c2 = (tid & 31) * 2, rr = tid >> 5;
#pragma unroll
  for (int it = 0; it < 8; ++it) {
    int r = it * 8 + rr;
    unsigned vv = *(const unsigned*)&Wm[(size_t)(k0 + r) * N + n0 + c2];
    t[c2][r] = (u16)vv;
    t[c2 + 1][r] = (u16)(vv >> 16);
  }
  __syncthreads();
#pragma unroll
  for (int it = 0; it < 8; ++it) {
    int n = it * 8 + rr;
    unsigned pk = (unsigned)t[n][c2] | ((unsigned)t[n][c2 + 1] << 16);
    *(unsigned*)&WTm[(size_t)(n0 + n) * K + k0 + c2] = pk;
  }
}

// ------------------------------- rope tables --------------------------------
__global__ __launch_bounds__(256) void rope_tab_k(const float* __restrict__ rot,
                                                  float* __restrict__ cost,
                                                  float* __restrict__ sint) {
  int id = blockIdx.x * 256 + threadIdx.x;
  if (id >= S_ * 32) return;
  int s = id >> 5, j = id & 31;
  cost[id] = rot[(size_t)s * 4096 + (size_t)(2 * j) * 64 + 2 * j];
  sint[id] = rot[(size_t)s * 4096 + (size_t)(2 * j + 1) * 64 + 2 * j];
}

// --------------------------------- rmsnorm 1 --------------------------------
__global__ __launch_bounds__(256) void rms1_k(const float* __restrict__ x,
                                              const float* __restrict__ rw,
                                              u16* __restrict__ y) {
  int row = blockIdx.x, tid = threadIdx.x;
  const float4 v = *(const float4*)&x[(size_t)row * HID_ + tid * 4];
  float ss = v.x * v.x + v.y * v.y + v.z * v.z + v.w * v.w;
#pragma unroll
  for (int o = 32; o; o >>= 1) ss += __shfl_xor(ss, o);
  __shared__ float red[4];
  if ((tid & 63) == 0) red[tid >> 6] = ss;
  __syncthreads();
  float rstd = rsqrtf((red[0] + red[1] + red[2] + red[3]) * (1.f / HID_) + 1e-6f);
  const float4 w4 = *(const float4*)&rw[tid * 4];
  ushort4 o4;
  o4.x = f2bf(v.x * rstd * w4.x);
  o4.y = f2bf(v.y * rstd * w4.y);
  o4.z = f2bf(v.z * rstd * w4.z);
  o4.w = f2bf(v.w * rstd * w4.w);
  *(ushort4*)&y[(size_t)row * HID_ + tid * 4] = o4;
}

// ------------------------- rmsnorm 2 + gate logits --------------------------
__global__ __launch_bounds__(256) void rms2_gate_k(const float* __restrict__ x2,
                                                   const float* __restrict__ rw,
                                                   const float* __restrict__ gw,
                                                   u16* __restrict__ y2,
                                                   float* __restrict__ logits) {
  int row = blockIdx.x, tid = threadIdx.x;
  int wv = tid >> 6, ln = tid & 63;
  const float4 v = *(const float4*)&x2[(size_t)row * HID_ + tid * 4];
  float ss = v.x * v.x + v.y * v.y + v.z * v.z + v.w * v.w;
#pragma unroll
  for (int o = 32; o; o >>= 1) ss += __shfl_xor(ss, o);
  __shared__ float red[4];
  __shared__ float lred[4][8];
  if (ln == 0) red[wv] = ss;
  __syncthreads();
  float rstd = rsqrtf((red[0] + red[1] + red[2] + red[3]) * (1.f / HID_) + 1e-6f);
  const float4 w4 = *(const float4*)&rw[tid * 4];
  float yv[4];
  yv[0] = v.x * rstd * w4.x; yv[1] = v.y * rstd * w4.y;
  yv[2] = v.z * rstd * w4.z; yv[3] = v.w * rstd * w4.w;
  ushort4 o4;
  o4.x = f2bf(yv[0]); o4.y = f2bf(yv[1]); o4.z = f2bf(yv[2]); o4.w = f2bf(yv[3]);
  *(ushort4*)&y2[(size_t)row * HID_ + tid * 4] = o4;
  float le[8] = {0, 0, 0, 0, 0, 0, 0, 0};
  int d0 = tid * 4;
#pragma unroll
  for (int j = 0; j < 4; ++j) {
    const float* grow = &gw[(size_t)(d0 + j) * NE_];
#pragma unroll
    for (int e = 0; e < 8; ++e) le[e] += yv[j] * grow[e];
  }
#pragma unroll
  for (int e = 0; e < 8; ++e) {
    float t = le[e];
#pragma unroll
    for (int o = 32; o; o >>= 1) t += __shfl_xor(t, o);
    le[e] = t;
  }
  if (ln == 0)
#pragma unroll
    for (int e = 0; e < 8; ++e) lred[wv][e] = le[e];
  __syncthreads();
  if (tid < 8)
    logits[(size_t)row * NE_ + tid] =
        lred[0][tid] + lred[1][tid] + lred[2][tid] + lred[3][tid];
}

// ------------------------------ top-2 routing -------------------------------
__global__ __launch_bounds__(256) void topk_k(const float* __restrict__ logits,
                                              int* __restrict__ topi,
                                              float* __restrict__ topg,
                                              int* __restrict__ counts) {
  int t = blockIdx.x * 256 + threadIdx.x;
  if (t >= S_) return;
  const float* lg = &logits[(size_t)t * NE_];
  float v0 = -1e30f; int i0 = 0;
#pragma unroll
  for (int e = 0; e < 8; ++e) {
    float x = lg[e];
    if (x > v0) { v0 = x; i0 = e; }
  }
  float v1 = -1e30f; int i1 = 0;
#pragma unroll
  for (int e = 0; e < 8; ++e) {
    if (e == i0) continue;
    float x = lg[e];
    if (x > v1) { v1 = x; i1 = e; }
  }
  float e1 = __expf(v1 - v0);
  topi[t * 2] = i0; topi[t * 2 + 1] = i1;
  topg[t * 2] = 1.f / (1.f + e1);
  topg[t * 2 + 1] = e1 / (1.f + e1);
  atomicAdd(&counts[i0], 1);
  atomicAdd(&counts[i1], 1);
}

__global__ void prefix_k(const int* __restrict__ counts, int* __restrict__ ebase) {
  if (threadIdx.x == 0) {
    int s = 0;
    for (int e = 0; e < 8; ++e) { ebase[e] = s; s += counts[e]; }
  }
}

__global__ __launch_bounds__(256) void scatter_k(const int* __restrict__ topi,
                                                 const int* __restrict__ ebase,
                                                 int* __restrict__ rank,
                                                 int* __restrict__ slot_token,
                                                 int* __restrict__ slot_of) {
  int t = blockIdx.x * 256 + threadIdx.x;
  if (t >= S_) return;
  for (int k = 0; k < 2; ++k) {
    int e = topi[t * 2 + k];
    int pos = ebase[e] + atomicAdd(&rank[e], 1);
    slot_token[pos] = t;
    slot_of[t * 2 + k] = pos;
  }
}

// --------------------------------- GEMM -------------------------------------
// 128x128 tile, BK=32, 4 waves (64x64 each = 4x4 frags).
// T3+T4 pipeline: 3 LDS buffers (48 KiB), global_load_lds width-16 staging,
// raw s_barrier + counted s_waitcnt vmcnt(4) -- prefetch survives barriers.
// Per iter: wait(own tile-t loads) -> barrier -> stage t+2 -> ds_read t -> MFMA.
// Buffer-reuse safety: buf[(t+2)%3] held tile t-1; every wave executed
// lgkmcnt(0) before passing the barrier, so its t-1 ds_reads are retired.
// MODE 0: qkv (z picks wq/wk/wv; rope for z<2; out head-major bf16)
// MODE 1: out-proj (+x residual, f32 out)
// MODE 2: ffn1 (z = e*2+mat; mat 0 -> w1/h1, 1 -> w3/h3; gathered A rows)
// MODE 3: ffn2 (compact rows, out eo bf16 [slot][1024])
template <int MODE>
__global__ __launch_bounds__(256) void gemm_k(
    const u16* __restrict__ A, const u16* __restrict__ B0,
    const u16* __restrict__ B1, const u16* __restrict__ B2, int K,
    const int* __restrict__ ecnt, const int* __restrict__ ebase,
    const int* __restrict__ slot_token, const float* __restrict__ cost,
    const float* __restrict__ sint, const float* __restrict__ xres,
    float* __restrict__ outf, u16* __restrict__ o0, u16* __restrict__ o1,
    u16* __restrict__ o2) {
  __shared__ alignas(16) char smem[49152];  // 3 bufs x (A 8KB + B 8KB)

  int m0 = blockIdx.x * 128, n0 = blockIdx.y * 128;
  int cnt = 0, base = 0;
  const u16* Bp;
  u16* outb = o0;
  int rope = 0;
  if constexpr (MODE == 0) {
    int z = blockIdx.z;
    Bp = (z == 0) ? B0 : (z == 1) ? B1 : B2;
    outb = (z == 0) ? o0 : (z == 1) ? o1 : o2;
    rope = (z < 2) ? 1 : 0;
  } else if constexpr (MODE == 1) {
    Bp = B0;
  } else if constexpr (MODE == 2) {
    int e = blockIdx.z >> 1, mat = blockIdx.z & 1;
    cnt = ecnt[e]; base = ebase[e];
    if (m0 >= cnt) return;
    Bp = (mat ? B1 : B0) + (size_t)e * DFF_ * HID_;
    outb = mat ? o1 : o0;
  } else {
    int e = blockIdx.z;
    cnt = ecnt[e]; base = ebase[e];
    if (m0 >= cnt) return;
    Bp = B0 + (size_t)e * HID_ * DFF_;
  }

  int tid = threadIdx.x, w = tid >> 6, l = tid & 63, lo = l & 15, g = l >> 4;
  int wm = w & 1, wn = w >> 1;
  int KT = K >> 5;

  // staging: lane covers tile rows r0 and r0+16, 16B unit u=l&3.
  // LDS dest linear; source column pre-swizzled (unit ^= (row>>1)&3).
  int r0 = w * 32 + (l >> 2);
  int r1 = r0 + 16;
  int u = l & 3;
  int sw0 = (u ^ ((r0 >> 1) & 3)) << 4;
  int sw1 = (u ^ ((r1 >> 1) & 3)) << 4;

  const char *pA0, *pA1;
  if constexpr (MODE == 2) {
    int t0 = slot_token[base + min(m0 + r0, cnt - 1)];
    int t1 = slot_token[base + min(m0 + r1, cnt - 1)];
    pA0 = (const char*)(A + (size_t)t0 * K) + sw0;
    pA1 = (const char*)(A + (size_t)t1 * K) + sw1;
  } else if constexpr (MODE == 3) {
    pA0 = (const char*)(A + (size_t)(base + min(m0 + r0, cnt - 1)) * K) + sw0;
    pA1 = (const char*)(A + (size_t)(base + min(m0 + r1, cnt - 1)) * K) + sw1;
  } else {
    pA0 = (const char*)(A + (size_t)(m0 + r0) * K) + sw0;
    pA1 = (const char*)(A + (size_t)(m0 + r1) * K) + sw1;
  }
  const char* pB0 = (const char*)(Bp + (size_t)(n0 + r0) * K) + sw0;
  const char* pB1 = (const char*)(Bp + (size_t)(n0 + r1) * K) + sw1;

  int wA0 = w * 2048, wA1 = w * 2048 + 1024;

  f32x4 acc[4][4];
#pragma unroll
  for (int i = 0; i < 4; ++i)
#pragma unroll
    for (int j = 0; j < 4; ++j) acc[i][j] = (f32x4){0.f, 0.f, 0.f, 0.f};

  // stage tile t into buffer buf (4 gloads per wave)
  auto stage = [&](int t, char* buf) {
    size_t kb = (size_t)t * 64;
    gload16(pA0 + kb, buf + wA0);
    gload16(pA1 + kb, buf + wA1);
    gload16(pB0 + kb, buf + 8192 + wA0);
    gload16(pB1 + kb, buf + 8192 + wA1);
  };

  // prologue: 2 tiles in flight
  stage(0, smem);
  stage(1, smem + 16384);

  for (int kt = 0; kt < KT; ++kt) {
    char* bufc = smem + (kt % 3) * 16384;
    if (kt + 1 < KT)
      asm volatile("s_waitcnt vmcnt(4) lgkmcnt(0)" ::: "memory");
    else
      asm volatile("s_waitcnt vmcnt(0) lgkmcnt(0)" ::: "memory");
    __builtin_amdgcn_s_barrier();
    if (kt + 2 < KT) stage(kt + 2, smem + ((kt + 2) % 3) * 16384);
    short8 af[4], bf_[4];
#pragma unroll
    for (int mi = 0; mi < 4; ++mi) {
      int r = wm * 64 + mi * 16 + lo;
      af[mi] = *(const short8*)(bufc + r * 64 + ((g ^ ((r >> 1) & 3)) << 4));
    }
#pragma unroll
    for (int ni = 0; ni < 4; ++ni) {
      int r = wn * 64 + ni * 16 + lo;
      bf_[ni] = *(const short8*)(bufc + 8192 + r * 64 + ((g ^ ((r >> 1) & 3)) << 4));
    }
#pragma unroll
    for (int mi = 0; mi < 4; ++mi)
#pragma unroll
      for (int ni = 0; ni < 4; ++ni)
        acc[mi][ni] = __builtin_amdgcn_mfma_f32_16x16x32_bf16(af[mi], bf_[ni], acc[mi][ni], 0, 0, 0);
  }

  // epilogue
#pragma unroll
  for (int mi = 0; mi < 4; ++mi) {
    int lr = wm * 64 + mi * 16 + g * 4;
#pragma unroll
    for (int ni = 0; ni < 4; ++ni) {
      int c = n0 + wn * 64 + ni * 16 + lo;
#pragma unroll
      for (int r = 0; r < 4; ++r) {
        float v = acc[mi][ni][r];
        if constexpr (MODE == 0) {
          int row = m0 + lr + r;
          float p = __shfl_xor(v, 1);
          if (rope) {
            int dd = c & 63;
            float co = cost[(size_t)row * 32 + (dd >> 1)];
            float si = sint[(size_t)row * 32 + (dd >> 1)];
            v = (dd & 1) ? (co * v - si * p) : (co * v + si * p);
          }
          outb[((size_t)(c >> 6) * S_ + row) * HD_ + (c & 63)] = f2bf(v);
        } else if constexpr (MODE == 1) {
          int row = m0 + lr + r;
          outf[(size_t)row * HID_ + c] = v + xres[(size_t)row * HID_ + c];
        } else if constexpr (MODE == 2) {
          int m = m0 + lr + r;
          if (m < cnt) outb[(size_t)(base + m) * DFF_ + c] = f2bf(v);
        } else {
          int m = m0 + lr + r;
          if (m < cnt) outb[(size_t)(base + m) * HID_ + c] = f2bf(v);
        }
      }
    }
  }
}

// ----------------------------- swiglu fuse ----------------------------------
__global__ __launch_bounds__(256) void swiglu_k(u16* __restrict__ h1,
                                                const u16* __restrict__ h3) {
  size_t i = ((size_t)blockIdx.x * 256 + threadIdx.x) * 8;
  short8 a = *(const short8*)(h1 + i);
  short8 b = *(const short8*)(h3 + i);
  short8 o;
#pragma unroll
  for (int j = 0; j < 8; ++j) {
    float x = bf2f((u16)a[j]), y = bf2f((u16)b[j]);
    float s = x / (1.f + __expf(-x));
    o[j] = (short)f2bf(s * y);
  }
  *(short8*)(h1 + i) = o;
}

// ------------------------------- attention ----------------------------------
__global__ __launch_bounds__(256) void attn_k(const u16* __restrict__ qh,
                                              const u16* __restrict__ kh,
                                              const u16* __restrict__ vht,
                                              u16* __restrict__ attn) {
  int qt = blockIdx.x, h = blockIdx.y;
  int tid = threadIdx.x, w = tid >> 6, l = tid & 63, lo = l & 15, g = l >> 4;
  __shared__ alignas(16) char Ks[8192];
  __shared__ alignas(16) char Vs[8192];
  __shared__ alignas(16) char Ps[8192];
  char* Pw = Ps + w * 2048;
  int q0 = qt * 64, qw = q0 + w * 16;
  const u16* qhh = qh + ((size_t)h * S_ + qw) * HD_;
  short8 bq0 = *(const short8*)(qhh + lo * 64 + g * 8);
  short8 bq1 = *(const short8*)(qhh + lo * 64 + 32 + g * 8);
  int q = qw + lo;
  float m_run = -1e30f, l_run = 0.f;
  f32x4 o[4];
#pragma unroll
  for (int i = 0; i < 4; ++i) o[i] = (f32x4){0.f, 0.f, 0.f, 0.f};
  int kt0 = max(0, q0 - (WIN_ - 1)) >> 6;
  for (int kt = kt0; kt <= qt; ++kt) {
    int kb = kt * 64;
    {
      int r0 = w * 16 + (l >> 3), r1 = r0 + 8;
      int uu = l & 7;
      short8 k0v = *(const short8*)(kh + ((size_t)h * S_ + kb + r0) * HD_ + uu * 8);
      short8 k1v = *(const short8*)(kh + ((size_t)h * S_ + kb + r1) * HD_ + uu * 8);
      short8 v0v = *(const short8*)(vht + ((size_t)h * HD_ + r0) * S_ + kb + uu * 8);
      short8 v1v = *(const short8*)(vht + ((size_t)h * HD_ + r1) * S_ + kb + uu * 8);
      *(short8*)(Ks + r0 * 128 + ((uu ^ (r0 & 7)) << 4)) = k0v;
      *(short8*)(Ks + r1 * 128 + ((uu ^ (r1 & 7)) << 4)) = k1v;
      *(short8*)(Vs + r0 * 128 + ((uu ^ (r0 & 7)) << 4)) = v0v;
      *(short8*)(Vs + r1 * 128 + ((uu ^ (r1 & 7)) << 4)) = v1v;
    }
    __syncthreads();
    f32x4 st[4];
#pragma unroll
    for (int kf = 0; kf < 4; ++kf) {
      int key = kf * 16 + lo;
      short8 a0 = *(const short8*)(Ks + key * 128 + ((g ^ (key & 7)) << 4));
      short8 a1 = *(const short8*)(Ks + key * 128 + (((4 + g) ^ (key & 7)) << 4));
      f32x4 z = (f32x4){0.f, 0.f, 0.f, 0.f};
      z = __builtin_amdgcn_mfma_f32_16x16x32_bf16(a0, bq0, z, 0, 0, 0);
      z = __builtin_amdgcn_mfma_f32_16x16x32_bf16(a1, bq1, z, 0, 0, 0);
      st[kf] = z;
    }
    float p[16];
    float tmax = -1e30f;
#pragma unroll
    for (int kf = 0; kf < 4; ++kf)
#pragma unroll
      for (int r = 0; r < 4; ++r) {
        int key = kb + kf * 16 + g * 4 + r;
        float s = st[kf][r] * 0.125f;
        bool okm = (key <= q) && (q - key < WIN_);
        s = okm ? s : -1e30f;
        p[kf * 4 + r] = s;
        tmax = fmaxf(tmax, s);
      }
    tmax = fmaxf(tmax, __shfl_xor(tmax, 16));
    tmax = fmaxf(tmax, __shfl_xor(tmax, 32));
    float m_new = fmaxf(m_run, tmax);
    float corr = __expf(m_run - m_new);
    float tsum = 0.f;
#pragma unroll
    for (int i = 0; i < 16; ++i) {
      float pe = (p[i] > -1e29f) ? __expf(p[i] - m_new) : 0.f;
      p[i] = pe;
      tsum += pe;
    }
    tsum += __shfl_xor(tsum, 16);
    tsum += __shfl_xor(tsum, 32);
    l_run = l_run * corr + tsum;
    m_run = m_new;
#pragma unroll
    for (int kf = 0; kf < 4; ++kf)
#pragma unroll
      for (int pr = 0; pr < 2; ++pr) {
        int keyloc = kf * 16 + g * 4 + pr * 2;
        unsigned pk = (unsigned)f2bf(p[kf * 4 + pr * 2]) |
                      ((unsigned)f2bf(p[kf * 4 + pr * 2 + 1]) << 16);
        *(unsigned*)(Pw + lo * 128 + (((keyloc >> 3) ^ (lo & 7)) << 4) +
                     (keyloc & 7) * 2) = pk;
      }
    float c0 = __shfl(corr, g * 4 + 0), c1 = __shfl(corr, g * 4 + 1);
    float c2 = __shfl(corr, g * 4 + 2), c3 = __shfl(corr, g * 4 + 3);
#pragma unroll
    for (int nf = 0; nf < 4; ++nf) {
      o[nf][0] *= c0; o[nf][1] *= c1; o[nf][2] *= c2; o[nf][3] *= c3;
    }
    short8 ap0 = *(const short8*)(Pw + lo * 128 + ((g ^ (lo & 7)) << 4));
    short8 ap1 = *(const short8*)(Pw + lo * 128 + (((4 + g) ^ (lo & 7)) << 4));
#pragma unroll
    for (int nf = 0; nf < 4; ++nf) {
      int d = nf * 16 + lo;
      short8 v0 = *(const short8*)(Vs + d * 128 + ((g ^ (d & 7)) << 4));
      short8 v1 = *(const short8*)(Vs + d * 128 + (((4 + g) ^ (d & 7)) << 4));
      o[nf] = __builtin_amdgcn_mfma_f32_16x16x32_bf16(ap0, v0, o[nf], 0, 0, 0);
      o[nf] = __builtin_amdgcn_mfma_f32_16x16x32_bf16(ap1, v1, o[nf], 0, 0, 0);
    }
    __syncthreads();
  }
  float linv = 1.f / l_run;
  float i0 = __shfl(linv, g * 4 + 0), i1 = __shfl(linv, g * 4 + 1);
  float i2 = __shfl(linv, g * 4 + 2), i3 = __shfl(linv, g * 4 + 3);
#pragma unroll
  for (int nf = 0; nf < 4; ++nf) {
    int d = nf * 16 + lo;
    attn[(size_t)(qw + g * 4 + 0) * HID_ + h * HD_ + d] = f2bf(o[nf][0] * i0);
    attn[(size_t)(qw + g * 4 + 1) * HID_ + h * HD_ + d] = f2bf(o[nf][1] * i1);
    attn[(size_t)(qw + g * 4 + 2) * HID_ + h * HD_ + d] = f2bf(o[nf][2] * i2);
    attn[(size_t)(qw + g * 4 + 3) * HID_ + h * HD_ + d] = f2bf(o[nf][3] * i3);
  }
}

// -------------------------------- combine -----------------------------------
__global__ __launch_bounds__(256) void combine_k(float* __restrict__ out,
                                                 const u16* __restrict__ eo,
                                                 const int* __restrict__ slot_of,
                                                 const float* __restrict__ topg) {
  int row = blockIdx.x, tid = threadIdx.x;
  int d0 = tid * 4;
  int p0 = slot_of[row * 2], p1 = slot_of[row * 2 + 1];
  float g0 = topg[row * 2], g1 = topg[row * 2 + 1];
  float4 cur = *(float4*)&out[(size_t)row * HID_ + d0];
  ushort4 ea = *(const ushort4*)&eo[(size_t)p0 * HID_ + d0];
  ushort4 eb = *(const ushort4*)&eo[(size_t)p1 * HID_ + d0];
  cur.x += g0 * bf2f(ea.x) + g1 * bf2f(eb.x);
  cur.y += g0 * bf2f(ea.y) + g1 * bf2f(eb.y);
  cur.z += g0 * bf2f(ea.z) + g1 * bf2f(eb.z);
  cur.w += g0 * bf2f(ea.w) + g1 * bf2f(eb.w);
  *(float4*)&out[(size_t)row * HID_ + d0] = cur;
}

// ------------------------------ host launcher -------------------------------
extern "C" void kernel_launch(void* const* d_in, const int* in_sizes, int n_in,
                              void* d_out, int out_size, void* d_ws,
                              size_t ws_size, hipStream_t stream) {
  const float* x = (const float*)d_in[0];
  const float* rot = (const float*)d_in[1];
  const float* r1w = (const float*)d_in[2];
  const float* wq = (const float*)d_in[3];
  const float* wk = (const float*)d_in[4];
  const float* wv = (const float*)d_in[5];
  const float* wo = (const float*)d_in[6];
  const float* r2w = (const float*)d_in[7];
  const float* gw = (const float*)d_in[8];
  const float* w1 = (const float*)d_in[9];
  const float* w2 = (const float*)d_in[10];
  const float* w3 = (const float*)d_in[11];
  float* out = (float*)d_out;

  char* ws = (char*)d_ws;
  size_t off = 0;
  auto alloc = [&](size_t bytes) {
    char* p = ws + off;
    off += (bytes + 255) & ~(size_t)255;
    return p;
  };
  const size_t MB4 = (size_t)S_ * HID_ * 2;  // 4 MiB
  u16* wqT = (u16*)alloc((size_t)HID_ * HID_ * 2);
  u16* wkT = (u16*)alloc((size_t)HID_ * HID_ * 2);
  u16* wvT = (u16*)alloc((size_t)HID_ * HID_ * 2);
  u16* woT = (u16*)alloc((size_t)HID_ * HID_ * 2);
  u16* w1T = (u16*)alloc((size_t)NE_ * DFF_ * HID_ * 2);
  u16* w3T = (u16*)alloc((size_t)NE_ * DFF_ * HID_ * 2);
  u16* w2T = (u16*)alloc((size_t)NE_ * HID_ * DFF_ * 2);
  char* uni = alloc((size_t)2 * S_ * DFF_ * 2);
  u16* ybf = (u16*)(uni);
  u16* qh = (u16*)(uni + MB4);
  u16* kh = (u16*)(uni + 2 * MB4);
  u16* vh = (u16*)(uni + 3 * MB4);
  u16* vht = (u16*)(uni + 4 * MB4);
  u16* attnb = (u16*)(uni + 5 * MB4);
  u16* h3 = (u16*)uni;  // alive only after attn phase
  u16* y2bf = (u16*)alloc(MB4);
  u16* h1 = (u16*)alloc((size_t)2 * S_ * DFF_ * 2);
  u16* eo = (u16*)alloc((size_t)2 * S_ * HID_ * 2);
  float* cost = (float*)alloc((size_t)S_ * 32 * 4);
  float* sint = (float*)alloc((size_t)S_ * 32 * 4);
  float* logits = (float*)alloc((size_t)S_ * NE_ * 4);
  int* topi = (int*)alloc((size_t)S_ * 2 * 4);
  float* topg = (float*)alloc((size_t)S_ * 2 * 4);
  int* ints = (int*)alloc(256);  // counts[8], rank[8], ebase[8]
  int* counts = ints;
  int* rank = ints + 8;
  int* ebase = ints + 16;
  int* slot_token = (int*)alloc((size_t)2 * S_ * 4);
  int* slot_of = (int*)alloc((size_t)S_ * 2 * 4);
  (void)ws_size; (void)in_sizes; (void)n_in; (void)out_size;

  hipMemsetAsync(counts, 0, 64, stream);  // counts + rank

  convT_f32_k<<<dim3(16, 16, 1), 256, 0, stream>>>(wq, wqT, HID_, HID_, (size_t)HID_ * HID_);
  convT_f32_k<<<dim3(16, 16, 1), 256, 0, stream>>>(wk, wkT, HID_, HID_, (size_t)HID_ * HID_);
  convT_f32_k<<<dim3(16, 16, 1), 256, 0, stream>>>(wv, wvT, HID_, HID_, (size_t)HID_ * HID_);
  convT_f32_k<<<dim3(16, 16, 1), 256, 0, stream>>>(wo, woT, HID_, HID_, (size_t)HID_ * HID_);
  convT_f32_k<<<dim3(64, 16, 8), 256, 0, stream>>>(w1, w1T, HID_, DFF_, (size_t)HID_ * DFF_);
  convT_f32_k<<<dim3(64, 16, 8), 256, 0, stream>>>(w3, w3T, HID_, DFF_, (size_t)HID_ * DFF_);
  convT_f32_k<<<dim3(16, 64, 8), 256, 0, stream>>>(w2, w2T, DFF_, HID_, (size_t)DFF_ * HID_);

  rope_tab_k<<<dim3(256), 256, 0, stream>>>(rot, cost, sint);
  rms1_k<<<dim3(S_), 256, 0, stream>>>(x, r1w, ybf);

  gemm_k<0><<<dim3(16, 8, 3), 256, 0, stream>>>(ybf, wqT, wkT, wvT, HID_, nullptr,
                                                nullptr, nullptr, cost, sint,
                                                nullptr, nullptr, qh, kh, vh);
  convT_u16_k<<<dim3(1, 32, 16), 256, 0, stream>>>(vh, vht, S_, HD_, (size_t)S_ * HD_);

  attn_k<<<dim3(32, 16), 256, 0, stream>>>(qh, kh, vht, attnb);

  gemm_k<1><<<dim3(16, 8, 1), 256, 0, stream>>>(attnb, woT, nullptr, nullptr, HID_,
                                                nullptr, nullptr, nullptr, nullptr,
                                                nullptr, x, out, nullptr, nullptr,
                                                nullptr);

  rms2_gate_k<<<dim3(S_), 256, 0, stream>>>(out, r2w, gw, y2bf, logits);
  topk_k<<<dim3(8), 256, 0, stream>>>(logits, topi, topg, counts);
  prefix_k<<<dim3(1), 64, 0, stream>>>(counts, ebase);
  scatter_k<<<dim3(8), 256, 0, stream>>>(topi, ebase, rank, slot_token, slot_of);

  // ffn1: z = e*2 + mat  (mat 0 -> w1/h1, 1 -> w3/h3)
  gemm_k<2><<<dim3(16, 32, 16), 256, 0, stream>>>(y2bf, w1T, w3T, nullptr, HID_,
                                                  counts, ebase, slot_token, nullptr,
                                                  nullptr, nullptr, nullptr, h1, h3,
                                                  nullptr);
  swiglu_k<<<dim3(8192), 256, 0, stream>>>(h1, h3);
  gemm_k<3><<<dim3(16, 8, 8), 256, 0, stream>>>(h1, w2T, nullptr, nullptr, DFF_,
                                                counts, ebase, slot_token, nullptr,
                                                nullptr, nullptr, nullptr, eo,
                                                nullptr, nullptr);
  combine_k<<<dim3(S_), 256, 0, stream>>>(out, eo, slot_of, topg);
}

// Round 4
// 709.575 us; speedup vs baseline: 1.3195x; 1.0807x over previous
//
#include <hip/hip_runtime.h>
#include <hip/hip_bf16.h>
#include <stdint.h>

// ---------------------------------------------------------------------------
// TransformerBlock: rms1 -> QKV(+RoPE) -> window-512 flash attn -> out-proj(+x)
//                   -> rms2(+gate logits) -> top2 route -> grouped SwiGLU MoE -> +x2
// Round 4: GEMMs on a 256^2 (8-wave) / 128^2 (4-wave) BK=64 4-phase schedule:
// per K-tile 4 phases {stage 2 gloads | ds_read frags | 16(8) MFMA | barrier},
// counted s_waitcnt vmcnt(2) twice per K-tile (never 0 in-loop), T2 swizzle,
// setprio around MFMA. FLOPs-per-stall x4 vs the 128^2 BK=32 structure.
// ---------------------------------------------------------------------------

#define S_ 2048
#define HID_ 1024
#define NH_ 16
#define HD_ 64
#define WIN_ 512
#define DFF_ 4096
#define NE_ 8

typedef unsigned short u16;
typedef __attribute__((ext_vector_type(8))) short short8;
typedef __attribute__((ext_vector_type(4))) float f32x4;

__device__ __forceinline__ u16 f2bf(float f) {
  union { float f; unsigned u; } v; v.f = f;
  unsigned r = (v.u + 0x7FFFu + ((v.u >> 16) & 1u)) >> 16;
  return (u16)r;
}
__device__ __forceinline__ float bf2f(u16 b) {
  union { unsigned u; float f; } v; v.u = ((unsigned)b) << 16;
  return v.f;
}

// async global->LDS, 16B per lane. LDS dest wave-uniform base + lane*16.
__device__ __forceinline__ void gload16(const void* g, void* l) {
  __builtin_amdgcn_global_load_lds(
      (const __attribute__((address_space(1))) void*)g,
      (__attribute__((address_space(3))) void*)l, 16, 0, 0);
}

// ------------------------- weight transpose+convert -------------------------
__global__ __launch_bounds__(256) void convT_f32_k(const float* __restrict__ W,
                                                   u16* __restrict__ WT,
                                                   int K, int N, size_t matStride) {
  __shared__ u16 t[64][66];
  const float* Wm = W + (size_t)blockIdx.z * matStride;
  u16* WTm = WT + (size_t)blockIdx.z * matStride;
  int n0 = blockIdx.x * 64, k0 = blockIdx.y * 64;
  int tid = threadIdx.x;
  int c2 = (tid & 31) * 2, rr = tid >> 5;
#pragma unroll
  for (int it = 0; it < 8; ++it) {
    int r = it * 8 + rr;
    float2 ab = *(const float2*)&Wm[(size_t)(k0 + r) * N + n0 + c2];
    t[c2][r] = f2bf(ab.x);
    t[c2 + 1][r] = f2bf(ab.y);
  }
  __syncthreads();
#pragma unroll
  for (int it = 0; it < 8; ++it) {
    int n = it * 8 + rr;
    unsigned pk = (unsigned)t[n][c2] | ((unsigned)t[n][c2 + 1] << 16);
    *(unsigned*)&WTm[(size_t)(n0 + n) * K + k0 + c2] = pk;
  }
}

// bf16 [K][N] -> bf16 [N][K] (for V: [s][d] -> [d][s] per head)
__global__ __launch_bounds__(256) void convT_u16_k(const u16* __restrict__ W,
                                                   u16* __restrict__ WT,
                                                   int K, int N, size_t matStride) {
  __shared__ u16 t[64][66];
  const u16* Wm = W + (size_t)blockIdx.z * matStride;
  u16* WTm = WT + (size_t)blockIdx.z * matStride;
  int n0 = blockIdx.x * 64, k0 = blockIdx.y * 64;
  int tid = threadIdx.x;
  int c2 = (tid & 31) * 2, rr = tid >> 5;
#pragma unroll
  for (int it = 0; it < 8; ++it) {
    int r = it * 8 + rr;
    unsigned vv = *(const unsigned*)&Wm[(size_t)(k0 + r) * N + n0 + c2];
    t[c2][r] = (u16)vv;
    t[c2 + 1][r] = (u16)(vv >> 16);
  }
  __syncthreads();
#pragma unroll
  for (int it = 0; it < 8; ++it) {
    int n = it * 8 + rr;
    unsigned pk = (unsigned)t[n][c2] | ((unsigned)t[n][c2 + 1] << 16);
    *(unsigned*)&WTm[(size_t)(n0 + n) * K + k0 + c2] = pk;
  }
}

// ------------------------------- rope tables --------------------------------
__global__ __launch_bounds__(256) void rope_tab_k(const float* __restrict__ rot,
                                                  float* __restrict__ cost,
                                                  float* __restrict__ sint) {
  int id = blockIdx.x * 256 + threadIdx.x;
  if (id >= S_ * 32) return;
  int s = id >> 5, j = id & 31;
  cost[id] = rot[(size_t)s * 4096 + (size_t)(2 * j) * 64 + 2 * j];
  sint[id] = rot[(size_t)s * 4096 + (size_t)(2 * j + 1) * 64 + 2 * j];
}

// --------------------------------- rmsnorm 1 --------------------------------
__global__ __launch_bounds__(256) void rms1_k(const float* __restrict__ x,
                                              const float* __restrict__ rw,
                                              u16* __restrict__ y) {
  int row = blockIdx.x, tid = threadIdx.x;
  const float4 v = *(const float4*)&x[(size_t)row * HID_ + tid * 4];
  float ss = v.x * v.x + v.y * v.y + v.z * v.z + v.w * v.w;
#pragma unroll
  for (int o = 32; o; o >>= 1) ss += __shfl_xor(ss, o);
  __shared__ float red[4];
  if ((tid & 63) == 0) red[tid >> 6] = ss;
  __syncthreads();
  float rstd = rsqrtf((red[0] + red[1] + red[2] + red[3]) * (1.f / HID_) + 1e-6f);
  const float4 w4 = *(const float4*)&rw[tid * 4];
  ushort4 o4;
  o4.x = f2bf(v.x * rstd * w4.x);
  o4.y = f2bf(v.y * rstd * w4.y);
  o4.z = f2bf(v.z * rstd * w4.z);
  o4.w = f2bf(v.w * rstd * w4.w);
  *(ushort4*)&y[(size_t)row * HID_ + tid * 4] = o4;
}

// ------------------------- rmsnorm 2 + gate logits --------------------------
__global__ __launch_bounds__(256) void rms2_gate_k(const float* __restrict__ x2,
                                                   const float* __restrict__ rw,
                                                   const float* __restrict__ gw,
                                                   u16* __restrict__ y2,
                                                   float* __restrict__ logits) {
  int row = blockIdx.x, tid = threadIdx.x;
  int wv = tid >> 6, ln = tid & 63;
  const float4 v = *(const float4*)&x2[(size_t)row * HID_ + tid * 4];
  float ss = v.x * v.x + v.y * v.y + v.z * v.z + v.w * v.w;
#pragma unroll
  for (int o = 32; o; o >>= 1) ss += __shfl_xor(ss, o);
  __shared__ float red[4];
  __shared__ float lred[4][8];
  if (ln == 0) red[wv] = ss;
  __syncthreads();
  float rstd = rsqrtf((red[0] + red[1] + red[2] + red[3]) * (1.f / HID_) + 1e-6f);
  const float4 w4 = *(const float4*)&rw[tid * 4];
  float yv[4];
  yv[0] = v.x * rstd * w4.x; yv[1] = v.y * rstd * w4.y;
  yv[2] = v.z * rstd * w4.z; yv[3] = v.w * rstd * w4.w;
  ushort4 o4;
  o4.x = f2bf(yv[0]); o4.y = f2bf(yv[1]); o4.z = f2bf(yv[2]); o4.w = f2bf(yv[3]);
  *(ushort4*)&y2[(size_t)row * HID_ + tid * 4] = o4;
  float le[8] = {0, 0, 0, 0, 0, 0, 0, 0};
  int d0 = tid * 4;
#pragma unroll
  for (int j = 0; j < 4; ++j) {
    const float* grow = &gw[(size_t)(d0 + j) * NE_];
#pragma unroll
    for (int e = 0; e < 8; ++e) le[e] += yv[j] * grow[e];
  }
#pragma unroll
  for (int e = 0; e < 8; ++e) {
    float t = le[e];
#pragma unroll
    for (int o = 32; o; o >>= 1) t += __shfl_xor(t, o);
    le[e] = t;
  }
  if (ln == 0)
#pragma unroll
    for (int e = 0; e < 8; ++e) lred[wv][e] = le[e];
  __syncthreads();
  if (tid < 8)
    logits[(size_t)row * NE_ + tid] =
        lred[0][tid] + lred[1][tid] + lred[2][tid] + lred[3][tid];
}

// ------------------------------ top-2 routing -------------------------------
__global__ __launch_bounds__(256) void topk_k(const float* __restrict__ logits,
                                              int* __restrict__ topi,
                                              float* __restrict__ topg,
                                              int* __restrict__ counts) {
  int t = blockIdx.x * 256 + threadIdx.x;
  if (t >= S_) return;
  const float* lg = &logits[(size_t)t * NE_];
  float v0 = -1e30f; int i0 = 0;
#pragma unroll
  for (int e = 0; e < 8; ++e) {
    float x = lg[e];
    if (x > v0) { v0 = x; i0 = e; }
  }
  float v1 = -1e30f; int i1 = 0;
#pragma unroll
  for (int e = 0; e < 8; ++e) {
    if (e == i0) continue;
    float x = lg[e];
    if (x > v1) { v1 = x; i1 = e; }
  }
  float e1 = __expf(v1 - v0);
  topi[t * 2] = i0; topi[t * 2 + 1] = i1;
  topg[t * 2] = 1.f / (1.f + e1);
  topg[t * 2 + 1] = e1 / (1.f + e1);
  atomicAdd(&counts[i0], 1);
  atomicAdd(&counts[i1], 1);
}

__global__ void prefix_k(const int* __restrict__ counts, int* __restrict__ ebase) {
  if (threadIdx.x == 0) {
    int s = 0;
    for (int e = 0; e < 8; ++e) { ebase[e] = s; s += counts[e]; }
  }
}

__global__ __launch_bounds__(256) void scatter_k(const int* __restrict__ topi,
                                                 const int* __restrict__ ebase,
                                                 int* __restrict__ rank,
                                                 int* __restrict__ slot_token,
                                                 int* __restrict__ slot_of) {
  int t = blockIdx.x * 256 + threadIdx.x;
  if (t >= S_) return;
  for (int k = 0; k < 2; ++k) {
    int e = topi[t * 2 + k];
    int pos = ebase[e] + atomicAdd(&rank[e], 1);
    slot_token[pos] = t;
    slot_of[t * 2 + k] = pos;
  }
}

// --------------------------------- GEMM -------------------------------------
// 4-phase BK=64 schedule. TPB=512: 256x256 tile, 8 waves (2M x 4N), wave tile
// 128x64, 16 MFMA/phase. TPB=256: 128x128, 4 waves (2x2), 8 MFMA/phase.
// LDS: A/B panels [BM][64] bf16 (128B rows), double-buffered.
// Per K-tile t: 4 phases (q, khalf); staging of tile t+1 spread 2 ops/phase
// (ph0: B j0,j1; ph1: B j2,j3; ph2: A j0,j2; ph3: A j1,j3). Counted waits:
// end-ph0 vmcnt(2) retires A j1,j3(t); end-ph3 vmcnt(2) retires all but
// A j1,j3(t+1). Never 0 except final tile. Swizzle: unit ^= row&7 applied on
// global source and ds_read (linear LDS dest, rule #21).
// MODE 0: qkv (z picks wq/wk/wv; rope for z<2; out head-major bf16)
// MODE 1: out-proj (+x residual, f32 out)
// MODE 2: ffn1 (z = e*2+mat; mat 0 -> w1/h1, 1 -> w3/h3; gathered A rows)
// MODE 3: ffn2 (compact rows, out eo bf16 [slot][1024])
template <int TPB, int MODE>
__global__ __launch_bounds__(TPB, 2) void gemm4_k(
    const u16* __restrict__ A, const u16* __restrict__ B0,
    const u16* __restrict__ B1, const u16* __restrict__ B2, int K,
    const int* __restrict__ ecnt, const int* __restrict__ ebase,
    const int* __restrict__ slot_token, const float* __restrict__ cost,
    const float* __restrict__ sint, const float* __restrict__ xres,
    float* __restrict__ outf, u16* __restrict__ o0, u16* __restrict__ o1,
    u16* __restrict__ o2) {
  constexpr int NW = TPB / 64;       // waves: 8 or 4
  constexpr int WN = NW / 2;         // n-waves: 4 or 2
  constexpr int BM = TPB / 2;        // 256 or 128
  constexpr int MROW = BM / 2;       // rows per m-wave: 128 or 64
  constexpr int MI = MROW / 16;      // m-frags: 8 or 4
  constexpr int MH = MI / 2;         // m-frags per phase: 4 or 2
  constexpr int ABYTES = BM * 128;   // one panel buffer
  __shared__ alignas(16) char smem[ABYTES * 4];
  char* ldsA = smem;
  char* ldsB = smem + 2 * ABYTES;

  int m0 = blockIdx.x * BM, n0 = blockIdx.y * BM;
  int cnt = 0, base = 0;
  const u16* Bp;
  u16* outb = o0;
  int rope = 0;
  if constexpr (MODE == 0) {
    int z = blockIdx.z;
    Bp = (z == 0) ? B0 : (z == 1) ? B1 : B2;
    outb = (z == 0) ? o0 : (z == 1) ? o1 : o2;
    rope = (z < 2) ? 1 : 0;
  } else if constexpr (MODE == 1) {
    Bp = B0;
  } else if constexpr (MODE == 2) {
    int e = blockIdx.z >> 1, mat = blockIdx.z & 1;
    cnt = ecnt[e]; base = ebase[e];
    if (m0 >= cnt) return;
    Bp = (mat ? B1 : B0) + (size_t)e * DFF_ * HID_;
    outb = mat ? o1 : o0;
  } else {
    int e = blockIdx.z;
    cnt = ecnt[e]; base = ebase[e];
    if (m0 >= cnt) return;
    Bp = B0 + (size_t)e * HID_ * DFF_;
  }

  int tid = threadIdx.x, w = tid >> 6, l = tid & 63, lo = l & 15, g = l >> 4;
  int wm = w / WN, wn = w % WN;
  int KT = K >> 6;
  size_t rb = (size_t)K * 2;  // row bytes

  // staging geometry: op j covers rows j*(BM/4) + w*8 .. +7; lane: row += l>>3,
  // 16B unit l&7, source column pre-swizzled by ^(row&7).
  int lrow = l >> 3, lu = l & 7;
  const char* pA[4];
  const char* pB[4];
  int ldOff[4];
#pragma unroll
  for (int j = 0; j < 4; ++j) {
    int rA = j * (BM / 4) + w * 8 + lrow;
    int swz = (lu ^ (rA & 7)) << 4;
    size_t arow;
    if constexpr (MODE == 2) {
      arow = (size_t)slot_token[base + min(m0 + rA, cnt - 1)];
    } else if constexpr (MODE == 3) {
      arow = (size_t)(base + min(m0 + rA, cnt - 1));
    } else {
      arow = (size_t)(m0 + rA);
    }
    pA[j] = (const char*)A + arow * rb + swz;
    pB[j] = (const char*)Bp + (size_t)(n0 + rA) * rb + swz;
    ldOff[j] = (j * (BM / 4) + w * 8) * 128;
  }

  auto stA = [&](int t, int j) {
    gload16(pA[j] + (size_t)t * 128, ldsA + (t & 1) * ABYTES + ldOff[j]);
  };
  auto stB = [&](int t, int j) {
    gload16(pB[j] + (size_t)t * 128, ldsB + (t & 1) * ABYTES + ldOff[j]);
  };
  auto rdA = [&](int d, int mi, int kh) {
    int row = wm * MROW + mi * 16 + lo;
    return *(const short8*)(ldsA + d * ABYTES + row * 128 +
                            (((kh * 4 + g) ^ (row & 7)) << 4));
  };
  auto rdB = [&](int d, int ni, int kh) {
    int row = wn * 64 + ni * 16 + lo;
    return *(const short8*)(ldsB + d * ABYTES + row * 128 +
                            (((kh * 4 + g) ^ (row & 7)) << 4));
  };

  f32x4 acc[MI][4];
#pragma unroll
  for (int i = 0; i < MI; ++i)
#pragma unroll
    for (int j = 0; j < 4; ++j) acc[i][j] = (f32x4){0.f, 0.f, 0.f, 0.f};

  // prologue: tile 0, canonical order (A j1,j3 last so vmcnt(2) leaves them)
  stB(0, 0); stB(0, 1); stB(0, 2); stB(0, 3);
  stA(0, 0); stA(0, 2); stA(0, 1); stA(0, 3);
  asm volatile("s_waitcnt vmcnt(2)" ::: "memory");
  __builtin_amdgcn_s_barrier();

  for (int t = 0; t < KT; ++t) {
    int d = t & 1;
    bool more = (t + 1 < KT);
    short8 afr[MH], bfr[4];
    // ---------------- phase 0: (q0, k0) ----------------
    if (more) { stB(t + 1, 0); stB(t + 1, 1); }
#pragma unroll
    for (int i = 0; i < MH; ++i) afr[i] = rdA(d, i, 0);
#pragma unroll
    for (int n = 0; n < 4; ++n) bfr[n] = rdB(d, n, 0);
    asm volatile("s_waitcnt lgkmcnt(0)" ::: "memory");
    __builtin_amdgcn_s_setprio(1);
#pragma unroll
    for (int i = 0; i < MH; ++i)
#pragma unroll
      for (int n = 0; n < 4; ++n)
        acc[i][n] = __builtin_amdgcn_mfma_f32_16x16x32_bf16(afr[i], bfr[n], acc[i][n], 0, 0, 0);
    __builtin_amdgcn_s_setprio(0);
    if (more) asm volatile("s_waitcnt vmcnt(2)" ::: "memory");
    else      asm volatile("s_waitcnt vmcnt(0)" ::: "memory");
    __builtin_amdgcn_s_barrier();
    // ---------------- phase 1: (q1, k0) ----------------
    if (more) { stB(t + 1, 2); stB(t + 1, 3); }
#pragma unroll
    for (int i = 0; i < MH; ++i) afr[i] = rdA(d, MH + i, 0);
    asm volatile("s_waitcnt lgkmcnt(0)" ::: "memory");
    __builtin_amdgcn_s_setprio(1);
#pragma unroll
    for (int i = 0; i < MH; ++i)
#pragma unroll
      for (int n = 0; n < 4; ++n)
        acc[MH + i][n] = __builtin_amdgcn_mfma_f32_16x16x32_bf16(afr[i], bfr[n], acc[MH + i][n], 0, 0, 0);
    __builtin_amdgcn_s_setprio(0);
    __builtin_amdgcn_s_barrier();
    // ---------------- phase 2: (q0, k1) ----------------
    if (more) { stA(t + 1, 0); stA(t + 1, 2); }
#pragma unroll
    for (int i = 0; i < MH; ++i) afr[i] = rdA(d, i, 1);
#pragma unroll
    for (int n = 0; n < 4; ++n) bfr[n] = rdB(d, n, 1);
    asm volatile("s_waitcnt lgkmcnt(0)" ::: "memory");
    __builtin_amdgcn_s_setprio(1);
#pragma unroll
    for (int i = 0; i < MH; ++i)
#pragma unroll
      for (int n = 0; n < 4; ++n)
        acc[i][n] = __builtin_amdgcn_mfma_f32_16x16x32_bf16(afr[i], bfr[n], acc[i][n], 0, 0, 0);
    __builtin_amdgcn_s_setprio(0);
    __builtin_amdgcn_s_barrier();
    // ---------------- phase 3: (q1, k1) ----------------
    if (more) { stA(t + 1, 1); stA(t + 1, 3); }
#pragma unroll
    for (int i = 0; i < MH; ++i) afr[i] = rdA(d, MH + i, 1);
    asm volatile("s_waitcnt lgkmcnt(0)" ::: "memory");
    __builtin_amdgcn_s_setprio(1);
#pragma unroll
    for (int i = 0; i < MH; ++i)
#pragma unroll
      for (int n = 0; n < 4; ++n)
        acc[MH + i][n] = __builtin_amdgcn_mfma_f32_16x16x32_bf16(afr[i], bfr[n], acc[MH + i][n], 0, 0, 0);
    __builtin_amdgcn_s_setprio(0);
    if (more) asm volatile("s_waitcnt vmcnt(2)" ::: "memory");
    __builtin_amdgcn_s_barrier();
  }

  // epilogue
#pragma unroll
  for (int mi = 0; mi < MI; ++mi) {
    int lr = wm * MROW + mi * 16 + g * 4;
#pragma unroll
    for (int ni = 0; ni < 4; ++ni) {
      int c = n0 + wn * 64 + ni * 16 + lo;
#pragma unroll
      for (int r = 0; r < 4; ++r) {
        float v = acc[mi][ni][r];
        if constexpr (MODE == 0) {
          int row = m0 + lr + r;
          float p = __shfl_xor(v, 1);
          if (rope) {
            int dd = c & 63;
            float co = cost[(size_t)row * 32 + (dd >> 1)];
            float si = sint[(size_t)row * 32 + (dd >> 1)];
            v = (dd & 1) ? (co * v - si * p) : (co * v + si * p);
          }
          outb[((size_t)(c >> 6) * S_ + row) * HD_ + (c & 63)] = f2bf(v);
        } else if constexpr (MODE == 1) {
          int row = m0 + lr + r;
          outf[(size_t)row * HID_ + c] = v + xres[(size_t)row * HID_ + c];
        } else if constexpr (MODE == 2) {
          int m = m0 + lr + r;
          if (m < cnt) outb[(size_t)(base + m) * DFF_ + c] = f2bf(v);
        } else {
          int m = m0 + lr + r;
          if (m < cnt) outb[(size_t)(base + m) * HID_ + c] = f2bf(v);
        }
      }
    }
  }
}

// ----------------------------- swiglu fuse ----------------------------------
__global__ __launch_bounds__(256) void swiglu_k(u16* __restrict__ h1,
                                                const u16* __restrict__ h3) {
  size_t i = ((size_t)blockIdx.x * 256 + threadIdx.x) * 8;
  short8 a = *(const short8*)(h1 + i);
  short8 b = *(const short8*)(h3 + i);
  short8 o;
#pragma unroll
  for (int j = 0; j < 8; ++j) {
    float x = bf2f((u16)a[j]), y = bf2f((u16)b[j]);
    float s = x / (1.f + __expf(-x));
    o[j] = (short)f2bf(s * y);
  }
  *(short8*)(h1 + i) = o;
}

// ------------------------------- attention ----------------------------------
__global__ __launch_bounds__(256) void attn_k(const u16* __restrict__ qh,
                                              const u16* __restrict__ kh,
                                              const u16* __restrict__ vht,
                                              u16* __restrict__ attn) {
  int qt = blockIdx.x, h = blockIdx.y;
  int tid = threadIdx.x, w = tid >> 6, l = tid & 63, lo = l & 15, g = l >> 4;
  __shared__ alignas(16) char Ks[8192];
  __shared__ alignas(16) char Vs[8192];
  __shared__ alignas(16) char Ps[8192];
  char* Pw = Ps + w * 2048;
  int q0 = qt * 64, qw = q0 + w * 16;
  const u16* qhh = qh + ((size_t)h * S_ + qw) * HD_;
  short8 bq0 = *(const short8*)(qhh + lo * 64 + g * 8);
  short8 bq1 = *(const short8*)(qhh + lo * 64 + 32 + g * 8);
  int q = qw + lo;
  float m_run = -1e30f, l_run = 0.f;
  f32x4 o[4];
#pragma unroll
  for (int i = 0; i < 4; ++i) o[i] = (f32x4){0.f, 0.f, 0.f, 0.f};
  int kt0 = max(0, q0 - (WIN_ - 1)) >> 6;
  for (int kt = kt0; kt <= qt; ++kt) {
    int kb = kt * 64;
    {
      int r0 = w * 16 + (l >> 3), r1 = r0 + 8;
      int uu = l & 7;
      short8 k0v = *(const short8*)(kh + ((size_t)h * S_ + kb + r0) * HD_ + uu * 8);
      short8 k1v = *(const short8*)(kh + ((size_t)h * S_ + kb + r1) * HD_ + uu * 8);
      short8 v0v = *(const short8*)(vht + ((size_t)h * HD_ + r0) * S_ + kb + uu * 8);
      short8 v1v = *(const short8*)(vht + ((size_t)h * HD_ + r1) * S_ + kb + uu * 8);
      *(short8*)(Ks + r0 * 128 + ((uu ^ (r0 & 7)) << 4)) = k0v;
      *(short8*)(Ks + r1 * 128 + ((uu ^ (r1 & 7)) << 4)) = k1v;
      *(short8*)(Vs + r0 * 128 + ((uu ^ (r0 & 7)) << 4)) = v0v;
      *(short8*)(Vs + r1 * 128 + ((uu ^ (r1 & 7)) << 4)) = v1v;
    }
    __syncthreads();
    f32x4 st[4];
#pragma unroll
    for (int kf = 0; kf < 4; ++kf) {
      int key = kf * 16 + lo;
      short8 a0 = *(const short8*)(Ks + key * 128 + ((g ^ (key & 7)) << 4));
      short8 a1 = *(const short8*)(Ks + key * 128 + (((4 + g) ^ (key & 7)) << 4));
      f32x4 z = (f32x4){0.f, 0.f, 0.f, 0.f};
      z = __builtin_amdgcn_mfma_f32_16x16x32_bf16(a0, bq0, z, 0, 0, 0);
      z = __builtin_amdgcn_mfma_f32_16x16x32_bf16(a1, bq1, z, 0, 0, 0);
      st[kf] = z;
    }
    float p[16];
    float tmax = -1e30f;
#pragma unroll
    for (int kf = 0; kf < 4; ++kf)
#pragma unroll
      for (int r = 0; r < 4; ++r) {
        int key = kb + kf * 16 + g * 4 + r;
        float s = st[kf][r] * 0.125f;
        bool okm = (key <= q) && (q - key < WIN_);
        s = okm ? s : -1e30f;
        p[kf * 4 + r] = s;
        tmax = fmaxf(tmax, s);
      }
    tmax = fmaxf(tmax, __shfl_xor(tmax, 16));
    tmax = fmaxf(tmax, __shfl_xor(tmax, 32));
    float m_new = fmaxf(m_run, tmax);
    float corr = __expf(m_run - m_new);
    float tsum = 0.f;
#pragma unroll
    for (int i = 0; i < 16; ++i) {
      float pe = (p[i] > -1e29f) ? __expf(p[i] - m_new) : 0.f;
      p[i] = pe;
      tsum += pe;
    }
    tsum += __shfl_xor(tsum, 16);
    tsum += __shfl_xor(tsum, 32);
    l_run = l_run * corr + tsum;
    m_run = m_new;
#pragma unroll
    for (int kf = 0; kf < 4; ++kf)
#pragma unroll
      for (int pr = 0; pr < 2; ++pr) {
        int keyloc = kf * 16 + g * 4 + pr * 2;
        unsigned pk = (unsigned)f2bf(p[kf * 4 + pr * 2]) |
                      ((unsigned)f2bf(p[kf * 4 + pr * 2 + 1]) << 16);
        *(unsigned*)(Pw + lo * 128 + (((keyloc >> 3) ^ (lo & 7)) << 4) +
                     (keyloc & 7) * 2) = pk;
      }
    float c0 = __shfl(corr, g * 4 + 0), c1 = __shfl(corr, g * 4 + 1);
    float c2 = __shfl(corr, g * 4 + 2), c3 = __shfl(corr, g * 4 + 3);
#pragma unroll
    for (int nf = 0; nf < 4; ++nf) {
      o[nf][0] *= c0; o[nf][1] *= c1; o[nf][2] *= c2; o[nf][3] *= c3;
    }
    short8 ap0 = *(const short8*)(Pw + lo * 128 + ((g ^ (lo & 7)) << 4));
    short8 ap1 = *(const short8*)(Pw + lo * 128 + (((4 + g) ^ (lo & 7)) << 4));
#pragma unroll
    for (int nf = 0; nf < 4; ++nf) {
      int d = nf * 16 + lo;
      short8 v0 = *(const short8*)(Vs + d * 128 + ((g ^ (d & 7)) << 4));
      short8 v1 = *(const short8*)(Vs + d * 128 + (((4 + g) ^ (d & 7)) << 4));
      o[nf] = __builtin_amdgcn_mfma_f32_16x16x32_bf16(ap0, v0, o[nf], 0, 0, 0);
      o[nf] = __builtin_amdgcn_mfma_f32_16x16x32_bf16(ap1, v1, o[nf], 0, 0, 0);
    }
    __syncthreads();
  }
  float linv = 1.f / l_run;
  float i0 = __shfl(linv, g * 4 + 0), i1 = __shfl(linv, g * 4 + 1);
  float i2 = __shfl(linv, g * 4 + 2), i3 = __shfl(linv, g * 4 + 3);
#pragma unroll
  for (int nf = 0; nf < 4; ++nf) {
    int d = nf * 16 + lo;
    attn[(size_t)(qw + g * 4 + 0) * HID_ + h * HD_ + d] = f2bf(o[nf][0] * i0);
    attn[(size_t)(qw + g * 4 + 1) * HID_ + h * HD_ + d] = f2bf(o[nf][1] * i1);
    attn[(size_t)(qw + g * 4 + 2) * HID_ + h * HD_ + d] = f2bf(o[nf][2] * i2);
    attn[(size_t)(qw + g * 4 + 3) * HID_ + h * HD_ + d] = f2bf(o[nf][3] * i3);
  }
}

// -------------------------------- combine -----------------------------------
__global__ __launch_bounds__(256) void combine_k(float* __restrict__ out,
                                                 const u16* __restrict__ eo,
                                                 const int* __restrict__ slot_of,
                                                 const float* __restrict__ topg) {
  int row = blockIdx.x, tid = threadIdx.x;
  int d0 = tid * 4;
  int p0 = slot_of[row * 2], p1 = slot_of[row * 2 + 1];
  float g0 = topg[row * 2], g1 = topg[row * 2 + 1];
  float4 cur = *(float4*)&out[(size_t)row * HID_ + d0];
  ushort4 ea = *(const ushort4*)&eo[(size_t)p0 * HID_ + d0];
  ushort4 eb = *(const ushort4*)&eo[(size_t)p1 * HID_ + d0];
  cur.x += g0 * bf2f(ea.x) + g1 * bf2f(eb.x);
  cur.y += g0 * bf2f(ea.y) + g1 * bf2f(eb.y);
  cur.z += g0 * bf2f(ea.z) + g1 * bf2f(eb.z);
  cur.w += g0 * bf2f(ea.w) + g1 * bf2f(eb.w);
  *(float4*)&out[(size_t)row * HID_ + d0] = cur;
}

// ------------------------------ host launcher -------------------------------
extern "C" void kernel_launch(void* const* d_in, const int* in_sizes, int n_in,
                              void* d_out, int out_size, void* d_ws,
                              size_t ws_size, hipStream_t stream) {
  const float* x = (const float*)d_in[0];
  const float* rot = (const float*)d_in[1];
  const float* r1w = (const float*)d_in[2];
  const float* wq = (const float*)d_in[3];
  const float* wk = (const float*)d_in[4];
  const float* wv = (const float*)d_in[5];
  const float* wo = (const float*)d_in[6];
  const float* r2w = (const float*)d_in[7];
  const float* gw = (const float*)d_in[8];
  const float* w1 = (const float*)d_in[9];
  const float* w2 = (const float*)d_in[10];
  const float* w3 = (const float*)d_in[11];
  float* out = (float*)d_out;

  char* ws = (char*)d_ws;
  size_t off = 0;
  auto alloc = [&](size_t bytes) {
    char* p = ws + off;
    off += (bytes + 255) & ~(size_t)255;
    return p;
  };
  const size_t MB4 = (size_t)S_ * HID_ * 2;  // 4 MiB
  u16* wqT = (u16*)alloc((size_t)HID_ * HID_ * 2);
  u16* wkT = (u16*)alloc((size_t)HID_ * HID_ * 2);
  u16* wvT = (u16*)alloc((size_t)HID_ * HID_ * 2);
  u16* woT = (u16*)alloc((size_t)HID_ * HID_ * 2);
  u16* w1T = (u16*)alloc((size_t)NE_ * DFF_ * HID_ * 2);
  u16* w3T = (u16*)alloc((size_t)NE_ * DFF_ * HID_ * 2);
  u16* w2T = (u16*)alloc((size_t)NE_ * HID_ * DFF_ * 2);
  char* uni = alloc((size_t)2 * S_ * DFF_ * 2);
  u16* ybf = (u16*)(uni);
  u16* qh = (u16*)(uni + MB4);
  u16* kh = (u16*)(uni + 2 * MB4);
  u16* vh = (u16*)(uni + 3 * MB4);
  u16* vht = (u16*)(uni + 4 * MB4);
  u16* attnb = (u16*)(uni + 5 * MB4);
  u16* h3 = (u16*)uni;  // alive only after attn phase
  u16* y2bf = (u16*)alloc(MB4);
  u16* h1 = (u16*)alloc((size_t)2 * S_ * DFF_ * 2);
  u16* eo = (u16*)alloc((size_t)2 * S_ * HID_ * 2);
  float* cost = (float*)alloc((size_t)S_ * 32 * 4);
  float* sint = (float*)alloc((size_t)S_ * 32 * 4);
  float* logits = (float*)alloc((size_t)S_ * NE_ * 4);
  int* topi = (int*)alloc((size_t)S_ * 2 * 4);
  float* topg = (float*)alloc((size_t)S_ * 2 * 4);
  int* ints = (int*)alloc(256);  // counts[8], rank[8], ebase[8]
  int* counts = ints;
  int* rank = ints + 8;
  int* ebase = ints + 16;
  int* slot_token = (int*)alloc((size_t)2 * S_ * 4);
  int* slot_of = (int*)alloc((size_t)S_ * 2 * 4);
  (void)ws_size; (void)in_sizes; (void)n_in; (void)out_size;

  hipMemsetAsync(counts, 0, 64, stream);  // counts + rank

  convT_f32_k<<<dim3(16, 16, 1), 256, 0, stream>>>(wq, wqT, HID_, HID_, (size_t)HID_ * HID_);
  convT_f32_k<<<dim3(16, 16, 1), 256, 0, stream>>>(wk, wkT, HID_, HID_, (size_t)HID_ * HID_);
  convT_f32_k<<<dim3(16, 16, 1), 256, 0, stream>>>(wv, wvT, HID_, HID_, (size_t)HID_ * HID_);
  convT_f32_k<<<dim3(16, 16, 1), 256, 0, stream>>>(wo, woT, HID_, HID_, (size_t)HID_ * HID_);
  convT_f32_k<<<dim3(64, 16, 8), 256, 0, stream>>>(w1, w1T, HID_, DFF_, (size_t)HID_ * DFF_);
  convT_f32_k<<<dim3(64, 16, 8), 256, 0, stream>>>(w3, w3T, HID_, DFF_, (size_t)HID_ * DFF_);
  convT_f32_k<<<dim3(16, 64, 8), 256, 0, stream>>>(w2, w2T, DFF_, HID_, (size_t)DFF_ * HID_);

  rope_tab_k<<<dim3(256), 256, 0, stream>>>(rot, cost, sint);
  rms1_k<<<dim3(S_), 256, 0, stream>>>(x, r1w, ybf);

  // QKV: 128^2 4-wave, grid (16 M, 8 N, 3 mats)
  gemm4_k<256, 0><<<dim3(16, 8, 3), 256, 0, stream>>>(
      ybf, wqT, wkT, wvT, HID_, nullptr, nullptr, nullptr, cost, sint, nullptr,
      nullptr, qh, kh, vh);
  convT_u16_k<<<dim3(1, 32, 16), 256, 0, stream>>>(vh, vht, S_, HD_, (size_t)S_ * HD_);

  attn_k<<<dim3(32, 16), 256, 0, stream>>>(qh, kh, vht, attnb);

  gemm4_k<256, 1><<<dim3(16, 8, 1), 256, 0, stream>>>(
      attnb, woT, nullptr, nullptr, HID_, nullptr, nullptr, nullptr, nullptr,
      nullptr, x, out, nullptr, nullptr, nullptr);

  rms2_gate_k<<<dim3(S_), 256, 0, stream>>>(out, r2w, gw, y2bf, logits);
  topk_k<<<dim3(8), 256, 0, stream>>>(logits, topi, topg, counts);
  prefix_k<<<dim3(1), 64, 0, stream>>>(counts, ebase);
  scatter_k<<<dim3(8), 256, 0, stream>>>(topi, ebase, rank, slot_token, slot_of);

  // ffn1: 256^2 8-wave, z = e*2 + mat (mat 0 -> w1/h1, 1 -> w3/h3)
  gemm4_k<512, 2><<<dim3(8, 16, 16), 512, 0, stream>>>(
      y2bf, w1T, w3T, nullptr, HID_, counts, ebase, slot_token, nullptr,
      nullptr, nullptr, nullptr, h1, h3, nullptr);
  swiglu_k<<<dim3(8192), 256, 0, stream>>>(h1, h3);
  // ffn2: 128^2 4-wave
  gemm4_k<256, 3><<<dim3(16, 8, 8), 256, 0, stream>>>(
      h1, w2T, nullptr, nullptr, DFF_, counts, ebase, slot_token, nullptr,
      nullptr, nullptr, nullptr, eo, nullptr, nullptr);
  combine_k<<<dim3(S_), 256, 0, stream>>>(out, eo, slot_of, topg);
}

// Round 5
// 454.618 us; speedup vs baseline: 2.0595x; 1.5608x over previous
//
#include <hip/hip_runtime.h>
#include <hip/hip_bf16.h>
#include <stdint.h>

// ---------------------------------------------------------------------------
// TransformerBlock: rms1 -> QKV(+RoPE) -> window-512 flash attn -> out-proj(+x)
//                   -> rms2(+gate logits) -> top2 route -> grouped SwiGLU MoE -> +x2
// Round 5: (1) GRID FIX: dense n-tile dim is blockIdx.x so active blocks cover
// all XCD residues (r4 put sparse m-tiles in x with gridDim.x%8==0 -> all MoE
// blocks landed on XCDs 0-1, 75% of the chip idle). (2) 4-phase K-loop with
// deepened staging: stage->use gap 3-5 phases, uniform vmcnt(4) at end-ph0 and
// end-ph3 (full FIFO ledger in comments), clamped-tail staging.
// ---------------------------------------------------------------------------

#define S_ 2048
#define HID_ 1024
#define NH_ 16
#define HD_ 64
#define WIN_ 512
#define DFF_ 4096
#define NE_ 8

typedef unsigned short u16;
typedef __attribute__((ext_vector_type(8))) short short8;
typedef __attribute__((ext_vector_type(4))) float f32x4;

__device__ __forceinline__ u16 f2bf(float f) {
  union { float f; unsigned u; } v; v.f = f;
  unsigned r = (v.u + 0x7FFFu + ((v.u >> 16) & 1u)) >> 16;
  return (u16)r;
}
__device__ __forceinline__ float bf2f(u16 b) {
  union { unsigned u; float f; } v; v.u = ((unsigned)b) << 16;
  return v.f;
}

// async global->LDS, 16B per lane. LDS dest wave-uniform base + lane*16.
__device__ __forceinline__ void gload16(const void* g, void* l) {
  __builtin_amdgcn_global_load_lds(
      (const __attribute__((address_space(1))) void*)g,
      (__attribute__((address_space(3))) void*)l, 16, 0, 0);
}

// ------------------------- weight transpose+convert -------------------------
__global__ __launch_bounds__(256) void convT_f32_k(const float* __restrict__ W,
                                                   u16* __restrict__ WT,
                                                   int K, int N, size_t matStride) {
  __shared__ u16 t[64][66];
  const float* Wm = W + (size_t)blockIdx.z * matStride;
  u16* WTm = WT + (size_t)blockIdx.z * matStride;
  int n0 = blockIdx.x * 64, k0 = blockIdx.y * 64;
  int tid = threadIdx.x;
  int c2 = (tid & 31) * 2, rr = tid >> 5;
#pragma unroll
  for (int it = 0; it < 8; ++it) {
    int r = it * 8 + rr;
    float2 ab = *(const float2*)&Wm[(size_t)(k0 + r) * N + n0 + c2];
    t[c2][r] = f2bf(ab.x);
    t[c2 + 1][r] = f2bf(ab.y);
  }
  __syncthreads();
#pragma unroll
  for (int it = 0; it < 8; ++it) {
    int n = it * 8 + rr;
    unsigned pk = (unsigned)t[n][c2] | ((unsigned)t[n][c2 + 1] << 16);
    *(unsigned*)&WTm[(size_t)(n0 + n) * K + k0 + c2] = pk;
  }
}

// bf16 [K][N] -> bf16 [N][K] (for V: [s][d] -> [d][s] per head)
__global__ __launch_bounds__(256) void convT_u16_k(const u16* __restrict__ W,
                                                   u16* __restrict__ WT,
                                                   int K, int N, size_t matStride) {
  __shared__ u16 t[64][66];
  const u16* Wm = W + (size_t)blockIdx.z * matStride;
  u16* WTm = WT + (size_t)blockIdx.z * matStride;
  int n0 = blockIdx.x * 64, k0 = blockIdx.y * 64;
  int tid = threadIdx.x;
  int c2 = (tid & 31) * 2, rr = tid >> 5;
#pragma unroll
  for (int it = 0; it < 8; ++it) {
    int r = it * 8 + rr;
    unsigned vv = *(const unsigned*)&Wm[(size_t)(k0 + r) * N + n0 + c2];
    t[c2][r] = (u16)vv;
    t[c2 + 1][r] = (u16)(vv >> 16);
  }
  __syncthreads();
#pragma unroll
  for (int it = 0; it < 8; ++it) {
    int n = it * 8 + rr;
    unsigned pk = (unsigned)t[n][c2] | ((unsigned)t[n][c2 + 1] << 16);
    *(unsigned*)&WTm[(size_t)(n0 + n) * K + k0 + c2] = pk;
  }
}

// ------------------------------- rope tables --------------------------------
__global__ __launch_bounds__(256) void rope_tab_k(const float* __restrict__ rot,
                                                  float* __restrict__ cost,
                                                  float* __restrict__ sint) {
  int id = blockIdx.x * 256 + threadIdx.x;
  if (id >= S_ * 32) return;
  int s = id >> 5, j = id & 31;
  cost[id] = rot[(size_t)s * 4096 + (size_t)(2 * j) * 64 + 2 * j];
  sint[id] = rot[(size_t)s * 4096 + (size_t)(2 * j + 1) * 64 + 2 * j];
}

// --------------------------------- rmsnorm 1 --------------------------------
__global__ __launch_bounds__(256) void rms1_k(const float* __restrict__ x,
                                              const float* __restrict__ rw,
                                              u16* __restrict__ y) {
  int row = blockIdx.x, tid = threadIdx.x;
  const float4 v = *(const float4*)&x[(size_t)row * HID_ + tid * 4];
  float ss = v.x * v.x + v.y * v.y + v.z * v.z + v.w * v.w;
#pragma unroll
  for (int o = 32; o; o >>= 1) ss += __shfl_xor(ss, o);
  __shared__ float red[4];
  if ((tid & 63) == 0) red[tid >> 6] = ss;
  __syncthreads();
  float rstd = rsqrtf((red[0] + red[1] + red[2] + red[3]) * (1.f / HID_) + 1e-6f);
  const float4 w4 = *(const float4*)&rw[tid * 4];
  ushort4 o4;
  o4.x = f2bf(v.x * rstd * w4.x);
  o4.y = f2bf(v.y * rstd * w4.y);
  o4.z = f2bf(v.z * rstd * w4.z);
  o4.w = f2bf(v.w * rstd * w4.w);
  *(ushort4*)&y[(size_t)row * HID_ + tid * 4] = o4;
}

// ------------------------- rmsnorm 2 + gate logits --------------------------
__global__ __launch_bounds__(256) void rms2_gate_k(const float* __restrict__ x2,
                                                   const float* __restrict__ rw,
                                                   const float* __restrict__ gw,
                                                   u16* __restrict__ y2,
                                                   float* __restrict__ logits) {
  int row = blockIdx.x, tid = threadIdx.x;
  int wv = tid >> 6, ln = tid & 63;
  const float4 v = *(const float4*)&x2[(size_t)row * HID_ + tid * 4];
  float ss = v.x * v.x + v.y * v.y + v.z * v.z + v.w * v.w;
#pragma unroll
  for (int o = 32; o; o >>= 1) ss += __shfl_xor(ss, o);
  __shared__ float red[4];
  __shared__ float lred[4][8];
  if (ln == 0) red[wv] = ss;
  __syncthreads();
  float rstd = rsqrtf((red[0] + red[1] + red[2] + red[3]) * (1.f / HID_) + 1e-6f);
  const float4 w4 = *(const float4*)&rw[tid * 4];
  float yv[4];
  yv[0] = v.x * rstd * w4.x; yv[1] = v.y * rstd * w4.y;
  yv[2] = v.z * rstd * w4.z; yv[3] = v.w * rstd * w4.w;
  ushort4 o4;
  o4.x = f2bf(yv[0]); o4.y = f2bf(yv[1]); o4.z = f2bf(yv[2]); o4.w = f2bf(yv[3]);
  *(ushort4*)&y2[(size_t)row * HID_ + tid * 4] = o4;
  float le[8] = {0, 0, 0, 0, 0, 0, 0, 0};
  int d0 = tid * 4;
#pragma unroll
  for (int j = 0; j < 4; ++j) {
    const float* grow = &gw[(size_t)(d0 + j) * NE_];
#pragma unroll
    for (int e = 0; e < 8; ++e) le[e] += yv[j] * grow[e];
  }
#pragma unroll
  for (int e = 0; e < 8; ++e) {
    float t = le[e];
#pragma unroll
    for (int o = 32; o; o >>= 1) t += __shfl_xor(t, o);
    le[e] = t;
  }
  if (ln == 0)
#pragma unroll
    for (int e = 0; e < 8; ++e) lred[wv][e] = le[e];
  __syncthreads();
  if (tid < 8)
    logits[(size_t)row * NE_ + tid] =
        lred[0][tid] + lred[1][tid] + lred[2][tid] + lred[3][tid];
}

// ------------------------------ top-2 routing -------------------------------
__global__ __launch_bounds__(256) void topk_k(const float* __restrict__ logits,
                                              int* __restrict__ topi,
                                              float* __restrict__ topg,
                                              int* __restrict__ counts) {
  int t = blockIdx.x * 256 + threadIdx.x;
  if (t >= S_) return;
  const float* lg = &logits[(size_t)t * NE_];
  float v0 = -1e30f; int i0 = 0;
#pragma unroll
  for (int e = 0; e < 8; ++e) {
    float x = lg[e];
    if (x > v0) { v0 = x; i0 = e; }
  }
  float v1 = -1e30f; int i1 = 0;
#pragma unroll
  for (int e = 0; e < 8; ++e) {
    if (e == i0) continue;
    float x = lg[e];
    if (x > v1) { v1 = x; i1 = e; }
  }
  float e1 = __expf(v1 - v0);
  topi[t * 2] = i0; topi[t * 2 + 1] = i1;
  topg[t * 2] = 1.f / (1.f + e1);
  topg[t * 2 + 1] = e1 / (1.f + e1);
  atomicAdd(&counts[i0], 1);
  atomicAdd(&counts[i1], 1);
}

__global__ void prefix_k(const int* __restrict__ counts, int* __restrict__ ebase) {
  if (threadIdx.x == 0) {
    int s = 0;
    for (int e = 0; e < 8; ++e) { ebase[e] = s; s += counts[e]; }
  }
}

__global__ __launch_bounds__(256) void scatter_k(const int* __restrict__ topi,
                                                 const int* __restrict__ ebase,
                                                 int* __restrict__ rank,
                                                 int* __restrict__ slot_token,
                                                 int* __restrict__ slot_of) {
  int t = blockIdx.x * 256 + threadIdx.x;
  if (t >= S_) return;
  for (int k = 0; k < 2; ++k) {
    int e = topi[t * 2 + k];
    int pos = ebase[e] + atomicAdd(&rank[e], 1);
    slot_token[pos] = t;
    slot_of[t * 2 + k] = pos;
  }
}

// --------------------------------- GEMM -------------------------------------
// BK=64, 4 phases/K-tile, double-buffered slots (slot[x&1] holds tile x).
// TPB=512: 256^2 tile, 8 waves (2M x 4N), wave 128x64, 16 MFMA/phase, LDS 128K.
// TPB=256: 128^2 tile, 4 waves (2M x 2N), wave  64x64,  8 MFMA/phase, LDS  64K.
// Staging ops: A/B panels split into 4 ops each (op j = rows j*(BM/4)+w*8+l>>3,
// 1 gload16/thread). Per iter t (uniform, staged tile idx clamped at tail):
//   ph0: stB(t+1,{0,1})  reads A(q0,k0)+B(k0)  MFMA  vmcnt(4)  barrier
//   ph1: stB(t+1,{2,3})  reads A(q1,k0)        MFMA            barrier
//   ph2: stA(t+1,{1,3})  reads A(q0,k1)+B(k1)  MFMA            barrier
//   ph3: stA(t+2,{0,2})  reads A(q1,k1)        MFMA  vmcnt(4)  barrier
// FIFO ledger (2 ops/phase): entry ph0 outstanding = {Aodd(t), Aeven(t+1)} = 4.
// end-ph0 vmcnt(4) retires Aodd(t) (needed ph1). end-ph3 vmcnt(4) retires
// B0123(t+1)+Aeven(t+... ) leaving {Aodd(t+1), Aeven(t+2)} -> ph0 reads ready.
// Slot safety: Aeven regions (q0) last read ph2; ph2-end barrier precedes ph3
// gloads. B/Aodd(t+1) go to the dead slot. Tail clamp rewrites identical bytes.
// MODE 0: qkv (z picks wq/wk/wv; rope for z<2; out head-major bf16)
// MODE 1: out-proj (+x residual, f32 out)
// MODE 2: ffn1 (z = e*2+mat; mat 0 -> w1/h1, 1 -> w3/h3; gathered A rows)
// MODE 3: ffn2 (compact rows, out eo bf16 [slot][1024])
template <int TPB, int MODE>
__global__ __launch_bounds__(TPB, 2) void gemm5_k(
    const u16* __restrict__ A, const u16* __restrict__ B0,
    const u16* __restrict__ B1, const u16* __restrict__ B2, int K,
    const int* __restrict__ ecnt, const int* __restrict__ ebase,
    const int* __restrict__ slot_token, const float* __restrict__ cost,
    const float* __restrict__ sint, const float* __restrict__ xres,
    float* __restrict__ outf, u16* __restrict__ o0, u16* __restrict__ o1,
    u16* __restrict__ o2) {
  constexpr int NW = TPB / 64;       // waves: 8 or 4
  constexpr int WN = NW / 2;         // n-waves: 4 or 2
  constexpr int BM = TPB / 2;        // 256 or 128
  constexpr int MROW = BM / 2;       // rows per m-wave: 128 or 64
  constexpr int MI = MROW / 16;      // m-frags: 8 or 4
  constexpr int MH = MI / 2;         // m-frags per phase: 4 or 2
  constexpr int ABYTES = BM * 128;   // one panel buffer
  __shared__ alignas(16) char smem[ABYTES * 4];
  char* ldsA = smem;
  char* ldsB = smem + 2 * ABYTES;

  // GRID: x = dense n-tiles (covers all XCD residues), y = m-tiles, z = mat/expert
  int n0 = blockIdx.x * BM, m0 = blockIdx.y * BM;
  int cnt = 0, base = 0;
  const u16* Bp;
  u16* outb = o0;
  int rope = 0;
  if constexpr (MODE == 0) {
    int z = blockIdx.z;
    Bp = (z == 0) ? B0 : (z == 1) ? B1 : B2;
    outb = (z == 0) ? o0 : (z == 1) ? o1 : o2;
    rope = (z < 2) ? 1 : 0;
  } else if constexpr (MODE == 1) {
    Bp = B0;
  } else if constexpr (MODE == 2) {
    int e = blockIdx.z >> 1, mat = blockIdx.z & 1;
    cnt = ecnt[e]; base = ebase[e];
    if (m0 >= cnt) return;
    Bp = (mat ? B1 : B0) + (size_t)e * DFF_ * HID_;
    outb = mat ? o1 : o0;
  } else {
    int e = blockIdx.z;
    cnt = ecnt[e]; base = ebase[e];
    if (m0 >= cnt) return;
    Bp = B0 + (size_t)e * HID_ * DFF_;
  }

  int tid = threadIdx.x, w = tid >> 6, l = tid & 63, lo = l & 15, g = l >> 4;
  int wm = w / WN, wn = w % WN;
  int KT = K >> 6;
  size_t rb = (size_t)K * 2;  // row bytes

  int lrow = l >> 3, lu = l & 7;
  const char* pA[4];
  const char* pB[4];
  int ldOff[4];
#pragma unroll
  for (int j = 0; j < 4; ++j) {
    int rA = j * (BM / 4) + w * 8 + lrow;
    int swz = (lu ^ (rA & 7)) << 4;
    size_t arow;
    if constexpr (MODE == 2) {
      arow = (size_t)slot_token[base + min(m0 + rA, cnt - 1)];
    } else if constexpr (MODE == 3) {
      arow = (size_t)(base + min(m0 + rA, cnt - 1));
    } else {
      arow = (size_t)(m0 + rA);
    }
    pA[j] = (const char*)A + arow * rb + swz;
    pB[j] = (const char*)Bp + (size_t)(n0 + rA) * rb + swz;
    ldOff[j] = (j * (BM / 4) + w * 8) * 128;
  }

  auto stA = [&](int t, int j) {
    gload16(pA[j] + (size_t)t * 128, ldsA + (t & 1) * ABYTES + ldOff[j]);
  };
  auto stB = [&](int t, int j) {
    gload16(pB[j] + (size_t)t * 128, ldsB + (t & 1) * ABYTES + ldOff[j]);
  };
  auto rdA = [&](int d, int mi, int kh) {
    int row = wm * MROW + mi * 16 + lo;
    return *(const short8*)(ldsA + d * ABYTES + row * 128 +
                            (((kh * 4 + g) ^ (row & 7)) << 4));
  };
  auto rdB = [&](int d, int ni, int kh) {
    int row = wn * 64 + ni * 16 + lo;
    return *(const short8*)(ldsB + d * ABYTES + row * 128 +
                            (((kh * 4 + g) ^ (row & 7)) << 4));
  };

  f32x4 acc[MI][4];
#pragma unroll
  for (int i = 0; i < MI; ++i)
#pragma unroll
    for (int j = 0; j < 4; ++j) acc[i][j] = (f32x4){0.f, 0.f, 0.f, 0.f};

  // prologue: tile 0 fully + A-even(1); order ends in steady-state FIFO.
  stB(0, 0); stB(0, 1); stB(0, 2); stB(0, 3);
  stA(0, 0); stA(0, 2);
  stA(0, 1); stA(0, 3);
  {
    int t1 = min(1, KT - 1);
    stA(t1, 0); stA(t1, 2);
  }
  asm volatile("s_waitcnt vmcnt(4)" ::: "memory");
  __builtin_amdgcn_s_barrier();

  for (int t = 0; t < KT; ++t) {
    int d = t & 1;
    int tn = min(t + 1, KT - 1);
    int tn2 = min(t + 2, KT - 1);
    short8 afr[MH], bfr[4];
    // ---------------- phase 0: (q0, k0) ----------------
    stB(tn, 0); stB(tn, 1);
#pragma unroll
    for (int i = 0; i < MH; ++i) afr[i] = rdA(d, i, 0);
#pragma unroll
    for (int n = 0; n < 4; ++n) bfr[n] = rdB(d, n, 0);
    asm volatile("s_waitcnt lgkmcnt(0)" ::: "memory");
    __builtin_amdgcn_s_setprio(1);
#pragma unroll
    for (int i = 0; i < MH; ++i)
#pragma unroll
      for (int n = 0; n < 4; ++n)
        acc[i][n] = __builtin_amdgcn_mfma_f32_16x16x32_bf16(afr[i], bfr[n], acc[i][n], 0, 0, 0);
    __builtin_amdgcn_s_setprio(0);
    asm volatile("s_waitcnt vmcnt(4)" ::: "memory");
    __builtin_amdgcn_s_barrier();
    // ---------------- phase 1: (q1, k0) ----------------
    stB(tn, 2); stB(tn, 3);
#pragma unroll
    for (int i = 0; i < MH; ++i) afr[i] = rdA(d, MH + i, 0);
    asm volatile("s_waitcnt lgkmcnt(0)" ::: "memory");
    __builtin_amdgcn_s_setprio(1);
#pragma unroll
    for (int i = 0; i < MH; ++i)
#pragma unroll
      for (int n = 0; n < 4; ++n)
        acc[MH + i][n] = __builtin_amdgcn_mfma_f32_16x16x32_bf16(afr[i], bfr[n], acc[MH + i][n], 0, 0, 0);
    __builtin_amdgcn_s_setprio(0);
    __builtin_amdgcn_s_barrier();
    // ---------------- phase 2: (q0, k1) ----------------
    stA(tn, 1); stA(tn, 3);
#pragma unroll
    for (int i = 0; i < MH; ++i) afr[i] = rdA(d, i, 1);
#pragma unroll
    for (int n = 0; n < 4; ++n) bfr[n] = rdB(d, n, 1);
    asm volatile("s_waitcnt lgkmcnt(0)" ::: "memory");
    __builtin_amdgcn_s_setprio(1);
#pragma unroll
    for (int i = 0; i < MH; ++i)
#pragma unroll
      for (int n = 0; n < 4; ++n)
        acc[i][n] = __builtin_amdgcn_mfma_f32_16x16x32_bf16(afr[i], bfr[n], acc[i][n], 0, 0, 0);
    __builtin_amdgcn_s_setprio(0);
    __builtin_amdgcn_s_barrier();
    // ---------------- phase 3: (q1, k1) ----------------
    stA(tn2, 0); stA(tn2, 2);
#pragma unroll
    for (int i = 0; i < MH; ++i) afr[i] = rdA(d, MH + i, 1);
    asm volatile("s_waitcnt lgkmcnt(0)" ::: "memory");
    __builtin_amdgcn_s_setprio(1);
#pragma unroll
    for (int i = 0; i < MH; ++i)
#pragma unroll
      for (int n = 0; n < 4; ++n)
        acc[MH + i][n] = __builtin_amdgcn_mfma_f32_16x16x32_bf16(afr[i], bfr[n], acc[MH + i][n], 0, 0, 0);
    __builtin_amdgcn_s_setprio(0);
    asm volatile("s_waitcnt vmcnt(4)" ::: "memory");
    __builtin_amdgcn_s_barrier();
  }
  // drain before LDS dealloc (pending gload_lds after endpgm would be unsafe)
  asm volatile("s_waitcnt vmcnt(0) lgkmcnt(0)" ::: "memory");

  // epilogue
#pragma unroll
  for (int mi = 0; mi < MI; ++mi) {
    int lr = wm * MROW + mi * 16 + g * 4;
#pragma unroll
    for (int ni = 0; ni < 4; ++ni) {
      int c = n0 + wn * 64 + ni * 16 + lo;
#pragma unroll
      for (int r = 0; r < 4; ++r) {
        float v = acc[mi][ni][r];
        if constexpr (MODE == 0) {
          int row = m0 + lr + r;
          float p = __shfl_xor(v, 1);
          if (rope) {
            int dd = c & 63;
            float co = cost[(size_t)row * 32 + (dd >> 1)];
            float si = sint[(size_t)row * 32 + (dd >> 1)];
            v = (dd & 1) ? (co * v - si * p) : (co * v + si * p);
          }
          outb[((size_t)(c >> 6) * S_ + row) * HD_ + (c & 63)] = f2bf(v);
        } else if constexpr (MODE == 1) {
          int row = m0 + lr + r;
          outf[(size_t)row * HID_ + c] = v + xres[(size_t)row * HID_ + c];
        } else if constexpr (MODE == 2) {
          int m = m0 + lr + r;
          if (m < cnt) outb[(size_t)(base + m) * DFF_ + c] = f2bf(v);
        } else {
          int m = m0 + lr + r;
          if (m < cnt) outb[(size_t)(base + m) * HID_ + c] = f2bf(v);
        }
      }
    }
  }
}

// ----------------------------- swiglu fuse ----------------------------------
__global__ __launch_bounds__(256) void swiglu_k(u16* __restrict__ h1,
                                                const u16* __restrict__ h3) {
  size_t i = ((size_t)blockIdx.x * 256 + threadIdx.x) * 8;
  short8 a = *(const short8*)(h1 + i);
  short8 b = *(const short8*)(h3 + i);
  short8 o;
#pragma unroll
  for (int j = 0; j < 8; ++j) {
    float x = bf2f((u16)a[j]), y = bf2f((u16)b[j]);
    float s = x / (1.f + __expf(-x));
    o[j] = (short)f2bf(s * y);
  }
  *(short8*)(h1 + i) = o;
}

// ------------------------------- attention ----------------------------------
__global__ __launch_bounds__(256) void attn_k(const u16* __restrict__ qh,
                                              const u16* __restrict__ kh,
                                              const u16* __restrict__ vht,
                                              u16* __restrict__ attn) {
  int qt = blockIdx.x, h = blockIdx.y;
  int tid = threadIdx.x, w = tid >> 6, l = tid & 63, lo = l & 15, g = l >> 4;
  __shared__ alignas(16) char Ks[8192];
  __shared__ alignas(16) char Vs[8192];
  __shared__ alignas(16) char Ps[8192];
  char* Pw = Ps + w * 2048;
  int q0 = qt * 64, qw = q0 + w * 16;
  const u16* qhh = qh + ((size_t)h * S_ + qw) * HD_;
  short8 bq0 = *(const short8*)(qhh + lo * 64 + g * 8);
  short8 bq1 = *(const short8*)(qhh + lo * 64 + 32 + g * 8);
  int q = qw + lo;
  float m_run = -1e30f, l_run = 0.f;
  f32x4 o[4];
#pragma unroll
  for (int i = 0; i < 4; ++i) o[i] = (f32x4){0.f, 0.f, 0.f, 0.f};
  int kt0 = max(0, q0 - (WIN_ - 1)) >> 6;
  for (int kt = kt0; kt <= qt; ++kt) {
    int kb = kt * 64;
    {
      int r0 = w * 16 + (l >> 3), r1 = r0 + 8;
      int uu = l & 7;
      short8 k0v = *(const short8*)(kh + ((size_t)h * S_ + kb + r0) * HD_ + uu * 8);
      short8 k1v = *(const short8*)(kh + ((size_t)h * S_ + kb + r1) * HD_ + uu * 8);
      short8 v0v = *(const short8*)(vht + ((size_t)h * HD_ + r0) * S_ + kb + uu * 8);
      short8 v1v = *(const short8*)(vht + ((size_t)h * HD_ + r1) * S_ + kb + uu * 8);
      *(short8*)(Ks + r0 * 128 + ((uu ^ (r0 & 7)) << 4)) = k0v;
      *(short8*)(Ks + r1 * 128 + ((uu ^ (r1 & 7)) << 4)) = k1v;
      *(short8*)(Vs + r0 * 128 + ((uu ^ (r0 & 7)) << 4)) = v0v;
      *(short8*)(Vs + r1 * 128 + ((uu ^ (r1 & 7)) << 4)) = v1v;
    }
    __syncthreads();
    f32x4 st[4];
#pragma unroll
    for (int kf = 0; kf < 4; ++kf) {
      int key = kf * 16 + lo;
      short8 a0 = *(const short8*)(Ks + key * 128 + ((g ^ (key & 7)) << 4));
      short8 a1 = *(const short8*)(Ks + key * 128 + (((4 + g) ^ (key & 7)) << 4));
      f32x4 z = (f32x4){0.f, 0.f, 0.f, 0.f};
      z = __builtin_amdgcn_mfma_f32_16x16x32_bf16(a0, bq0, z, 0, 0, 0);
      z = __builtin_amdgcn_mfma_f32_16x16x32_bf16(a1, bq1, z, 0, 0, 0);
      st[kf] = z;
    }
    float p[16];
    float tmax = -1e30f;
#pragma unroll
    for (int kf = 0; kf < 4; ++kf)
#pragma unroll
      for (int r = 0; r < 4; ++r) {
        int key = kb + kf * 16 + g * 4 + r;
        float s = st[kf][r] * 0.125f;
        bool okm = (key <= q) && (q - key < WIN_);
        s = okm ? s : -1e30f;
        p[kf * 4 + r] = s;
        tmax = fmaxf(tmax, s);
      }
    tmax = fmaxf(tmax, __shfl_xor(tmax, 16));
    tmax = fmaxf(tmax, __shfl_xor(tmax, 32));
    float m_new = fmaxf(m_run, tmax);
    float corr = __expf(m_run - m_new);
    float tsum = 0.f;
#pragma unroll
    for (int i = 0; i < 16; ++i) {
      float pe = (p[i] > -1e29f) ? __expf(p[i] - m_new) : 0.f;
      p[i] = pe;
      tsum += pe;
    }
    tsum += __shfl_xor(tsum, 16);
    tsum += __shfl_xor(tsum, 32);
    l_run = l_run * corr + tsum;
    m_run = m_new;
#pragma unroll
    for (int kf = 0; kf < 4; ++kf)
#pragma unroll
      for (int pr = 0; pr < 2; ++pr) {
        int keyloc = kf * 16 + g * 4 + pr * 2;
        unsigned pk = (unsigned)f2bf(p[kf * 4 + pr * 2]) |
                      ((unsigned)f2bf(p[kf * 4 + pr * 2 + 1]) << 16);
        *(unsigned*)(Pw + lo * 128 + (((keyloc >> 3) ^ (lo & 7)) << 4) +
                     (keyloc & 7) * 2) = pk;
      }
    float c0 = __shfl(corr, g * 4 + 0), c1 = __shfl(corr, g * 4 + 1);
    float c2 = __shfl(corr, g * 4 + 2), c3 = __shfl(corr, g * 4 + 3);
#pragma unroll
    for (int nf = 0; nf < 4; ++nf) {
      o[nf][0] *= c0; o[nf][1] *= c1; o[nf][2] *= c2; o[nf][3] *= c3;
    }
    short8 ap0 = *(const short8*)(Pw + lo * 128 + ((g ^ (lo & 7)) << 4));
    short8 ap1 = *(const short8*)(Pw + lo * 128 + (((4 + g) ^ (lo & 7)) << 4));
#pragma unroll
    for (int nf = 0; nf < 4; ++nf) {
      int d = nf * 16 + lo;
      short8 v0 = *(const short8*)(Vs + d * 128 + ((g ^ (d & 7)) << 4));
      short8 v1 = *(const short8*)(Vs + d * 128 + (((4 + g) ^ (d & 7)) << 4));
      o[nf] = __builtin_amdgcn_mfma_f32_16x16x32_bf16(ap0, v0, o[nf], 0, 0, 0);
      o[nf] = __builtin_amdgcn_mfma_f32_16x16x32_bf16(ap1, v1, o[nf], 0, 0, 0);
    }
    __syncthreads();
  }
  float linv = 1.f / l_run;
  float i0 = __shfl(linv, g * 4 + 0), i1 = __shfl(linv, g * 4 + 1);
  float i2 = __shfl(linv, g * 4 + 2), i3 = __shfl(linv, g * 4 + 3);
#pragma unroll
  for (int nf = 0; nf < 4; ++nf) {
    int d = nf * 16 + lo;
    attn[(size_t)(qw + g * 4 + 0) * HID_ + h * HD_ + d] = f2bf(o[nf][0] * i0);
    attn[(size_t)(qw + g * 4 + 1) * HID_ + h * HD_ + d] = f2bf(o[nf][1] * i1);
    attn[(size_t)(qw + g * 4 + 2) * HID_ + h * HD_ + d] = f2bf(o[nf][2] * i2);
    attn[(size_t)(qw + g * 4 + 3) * HID_ + h * HD_ + d] = f2bf(o[nf][3] * i3);
  }
}

// -------------------------------- combine -----------------------------------
__global__ __launch_bounds__(256) void combine_k(float* __restrict__ out,
                                                 const u16* __restrict__ eo,
                                                 const int* __restrict__ slot_of,
                                                 const float* __restrict__ topg) {
  int row = blockIdx.x, tid = threadIdx.x;
  int d0 = tid * 4;
  int p0 = slot_of[row * 2], p1 = slot_of[row * 2 + 1];
  float g0 = topg[row * 2], g1 = topg[row * 2 + 1];
  float4 cur = *(float4*)&out[(size_t)row * HID_ + d0];
  ushort4 ea = *(const ushort4*)&eo[(size_t)p0 * HID_ + d0];
  ushort4 eb = *(const ushort4*)&eo[(size_t)p1 * HID_ + d0];
  cur.x += g0 * bf2f(ea.x) + g1 * bf2f(eb.x);
  cur.y += g0 * bf2f(ea.y) + g1 * bf2f(eb.y);
  cur.z += g0 * bf2f(ea.z) + g1 * bf2f(eb.z);
  cur.w += g0 * bf2f(ea.w) + g1 * bf2f(eb.w);
  *(float4*)&out[(size_t)row * HID_ + d0] = cur;
}

// ------------------------------ host launcher -------------------------------
extern "C" void kernel_launch(void* const* d_in, const int* in_sizes, int n_in,
                              void* d_out, int out_size, void* d_ws,
                              size_t ws_size, hipStream_t stream) {
  const float* x = (const float*)d_in[0];
  const float* rot = (const float*)d_in[1];
  const float* r1w = (const float*)d_in[2];
  const float* wq = (const float*)d_in[3];
  const float* wk = (const float*)d_in[4];
  const float* wv = (const float*)d_in[5];
  const float* wo = (const float*)d_in[6];
  const float* r2w = (const float*)d_in[7];
  const float* gw = (const float*)d_in[8];
  const float* w1 = (const float*)d_in[9];
  const float* w2 = (const float*)d_in[10];
  const float* w3 = (const float*)d_in[11];
  float* out = (float*)d_out;

  char* ws = (char*)d_ws;
  size_t off = 0;
  auto alloc = [&](size_t bytes) {
    char* p = ws + off;
    off += (bytes + 255) & ~(size_t)255;
    return p;
  };
  const size_t MB4 = (size_t)S_ * HID_ * 2;  // 4 MiB
  u16* wqT = (u16*)alloc((size_t)HID_ * HID_ * 2);
  u16* wkT = (u16*)alloc((size_t)HID_ * HID_ * 2);
  u16* wvT = (u16*)alloc((size_t)HID_ * HID_ * 2);
  u16* woT = (u16*)alloc((size_t)HID_ * HID_ * 2);
  u16* w1T = (u16*)alloc((size_t)NE_ * DFF_ * HID_ * 2);
  u16* w3T = (u16*)alloc((size_t)NE_ * DFF_ * HID_ * 2);
  u16* w2T = (u16*)alloc((size_t)NE_ * HID_ * DFF_ * 2);
  char* uni = alloc((size_t)2 * S_ * DFF_ * 2);
  u16* ybf = (u16*)(uni);
  u16* qh = (u16*)(uni + MB4);
  u16* kh = (u16*)(uni + 2 * MB4);
  u16* vh = (u16*)(uni + 3 * MB4);
  u16* vht = (u16*)(uni + 4 * MB4);
  u16* attnb = (u16*)(uni + 5 * MB4);
  u16* h3 = (u16*)uni;  // alive only after attn phase
  u16* y2bf = (u16*)alloc(MB4);
  u16* h1 = (u16*)alloc((size_t)2 * S_ * DFF_ * 2);
  u16* eo = (u16*)alloc((size_t)2 * S_ * HID_ * 2);
  float* cost = (float*)alloc((size_t)S_ * 32 * 4);
  float* sint = (float*)alloc((size_t)S_ * 32 * 4);
  float* logits = (float*)alloc((size_t)S_ * NE_ * 4);
  int* topi = (int*)alloc((size_t)S_ * 2 * 4);
  float* topg = (float*)alloc((size_t)S_ * 2 * 4);
  int* ints = (int*)alloc(256);  // counts[8], rank[8], ebase[8]
  int* counts = ints;
  int* rank = ints + 8;
  int* ebase = ints + 16;
  int* slot_token = (int*)alloc((size_t)2 * S_ * 4);
  int* slot_of = (int*)alloc((size_t)S_ * 2 * 4);
  (void)ws_size; (void)in_sizes; (void)n_in; (void)out_size;

  hipMemsetAsync(counts, 0, 64, stream);  // counts + rank

  convT_f32_k<<<dim3(16, 16, 1), 256, 0, stream>>>(wq, wqT, HID_, HID_, (size_t)HID_ * HID_);
  convT_f32_k<<<dim3(16, 16, 1), 256, 0, stream>>>(wk, wkT, HID_, HID_, (size_t)HID_ * HID_);
  convT_f32_k<<<dim3(16, 16, 1), 256, 0, stream>>>(wv, wvT, HID_, HID_, (size_t)HID_ * HID_);
  convT_f32_k<<<dim3(16, 16, 1), 256, 0, stream>>>(wo, woT, HID_, HID_, (size_t)HID_ * HID_);
  convT_f32_k<<<dim3(64, 16, 8), 256, 0, stream>>>(w1, w1T, HID_, DFF_, (size_t)HID_ * DFF_);
  convT_f32_k<<<dim3(64, 16, 8), 256, 0, stream>>>(w3, w3T, HID_, DFF_, (size_t)HID_ * DFF_);
  convT_f32_k<<<dim3(16, 64, 8), 256, 0, stream>>>(w2, w2T, DFF_, HID_, (size_t)DFF_ * HID_);

  rope_tab_k<<<dim3(256), 256, 0, stream>>>(rot, cost, sint);
  rms1_k<<<dim3(S_), 256, 0, stream>>>(x, r1w, ybf);

  // QKV: 128^2 4-wave, grid (n=8, m=16, 3 mats)
  gemm5_k<256, 0><<<dim3(8, 16, 3), 256, 0, stream>>>(
      ybf, wqT, wkT, wvT, HID_, nullptr, nullptr, nullptr, cost, sint, nullptr,
      nullptr, qh, kh, vh);
  convT_u16_k<<<dim3(1, 32, 16), 256, 0, stream>>>(vh, vht, S_, HD_, (size_t)S_ * HD_);

  attn_k<<<dim3(32, 16), 256, 0, stream>>>(qh, kh, vht, attnb);

  gemm5_k<256, 1><<<dim3(8, 16, 1), 256, 0, stream>>>(
      attnb, woT, nullptr, nullptr, HID_, nullptr, nullptr, nullptr, nullptr,
      nullptr, x, out, nullptr, nullptr, nullptr);

  rms2_gate_k<<<dim3(S_), 256, 0, stream>>>(out, r2w, gw, y2bf, logits);
  topk_k<<<dim3(8), 256, 0, stream>>>(logits, topi, topg, counts);
  prefix_k<<<dim3(1), 64, 0, stream>>>(counts, ebase);
  scatter_k<<<dim3(8), 256, 0, stream>>>(topi, ebase, rank, slot_token, slot_of);

  // ffn1: 256^2 8-wave, grid (n=16, m=8, z=e*2+mat) -- dense x covers all XCDs
  gemm5_k<512, 2><<<dim3(16, 8, 16), 512, 0, stream>>>(
      y2bf, w1T, w3T, nullptr, HID_, counts, ebase, slot_token, nullptr,
      nullptr, nullptr, nullptr, h1, h3, nullptr);
  swiglu_k<<<dim3(8192), 256, 0, stream>>>(h1, h3);
  // ffn2: 128^2 4-wave, grid (n=8, m=16, e)
  gemm5_k<256, 3><<<dim3(8, 16, 8), 256, 0, stream>>>(
      h1, w2T, nullptr, nullptr, DFF_, counts, ebase, slot_token, nullptr,
      nullptr, nullptr, nullptr, eo, nullptr, nullptr);
  combine_k<<<dim3(S_), 256, 0, stream>>>(out, eo, slot_of, topg);
}